// Round 1
// baseline (489.810 us; speedup 1.0000x reference)
//
#include <hip/hip_runtime.h>
#include <cstdint>

typedef unsigned short u16;
typedef __attribute__((ext_vector_type(8))) short short8;   // bf16x8 MFMA frag
typedef __attribute__((ext_vector_type(4))) short short4v;  // bf16x4
typedef __attribute__((ext_vector_type(4))) float f32x4;    // fp32x4 accumulator

#define SEQ     2048
#define NHEADS  32
#define NKV     8
#define HD      64
#define DM      2048
#define MROWS   4096   // BATCH * SEQ
#define KVSTR   1024   // fused KV row stride (8 K-heads | 8 V-heads)
#define PSTR    88     // Ps row stride (u16): 176B, 16B-aligned, 2-way banks

__device__ __forceinline__ float b2f(unsigned int u) {
    return __builtin_bit_cast(float, u << 16);
}
__device__ __forceinline__ u16 f2b(float f) {
    unsigned int u = __builtin_bit_cast(unsigned int, f);
    return (u16)((u + 0x7fffu + ((u >> 16) & 1u)) >> 16);   // RNE
}

// async global->LDS, 16B per lane; LDS dest = wave-uniform base + lane*16
#define GLOAD_LDS16(g, l)                                              \
    __builtin_amdgcn_global_load_lds(                                  \
        (const __attribute__((address_space(1))) void*)(g),            \
        (__attribute__((address_space(3))) void*)(l), 16, 0, 0)

// ------------------------------------------------------------- f32 -> bf16
__global__ __launch_bounds__(256) void cvt_f32_bf16(
    const float* __restrict__ in, u16* __restrict__ out, int n4) {
    int i = blockIdx.x * 256 + threadIdx.x;
    if (i < n4) {
        float4 v = ((const float4*)in)[i];
        ushort4 o;
        o.x = f2b(v.x); o.y = f2b(v.y); o.z = f2b(v.z); o.w = f2b(v.w);
        ((ushort4*)out)[i] = o;
    }
}

// ------------------------------------------------------------- RoPE tables
__global__ __launch_bounds__(256) void rope_table_kernel(
    float* __restrict__ cosT, float* __restrict__ sinT) {
    int idx = blockIdx.x * 256 + threadIdx.x;     // 65536 = 2048*32
    int s  = idx >> 5;
    int dl = idx & 31;
    float inv_freq = exp2f((float)dl * -0.41524101186092025f); // 10000^(-dl/32)
    float ang = (float)s * inv_freq;
    float sn, cs;
    sincosf(ang, &sn, &cs);                        // accurate (range-reduced)
    cosT[idx] = cs;
    sinT[idx] = sn;
}

// ------------------------------------------------- transpose + downcast
__global__ __launch_bounds__(256) void transpose_f32_bf16(
    const float* __restrict__ in, u16* __restrict__ out, int K, int N) {
    __shared__ float tile[32][33];
    int n0 = blockIdx.x * 32, k0 = blockIdx.y * 32;
    int tx = threadIdx.x, ty = threadIdx.y;   // 32 x 8
    for (int r = ty; r < 32; r += 8)
        tile[r][tx] = in[(size_t)(k0 + r) * N + n0 + tx];
    __syncthreads();
    for (int r = ty; r < 32; r += 8)
        out[(size_t)(n0 + r) * K + k0 + tx] = f2b(tile[tx][r]);
}

// ------------------------------------------------------- GEMM core macro
// 128x128 block tile, 4 waves 2x2 (64x64 each, acc 4x4), BK=32, unpadded
// LDS, global_load_lds width=16 (m97 structure).
#define GEMM_BODY(A, BT, Kdim)                                             \
    constexpr int BK = 32;                                                 \
    __shared__ __align__(16) u16 As[128 * BK];                             \
    __shared__ __align__(16) u16 Bs[128 * BK];                             \
    const int tid  = threadIdx.x;                                          \
    const int wid  = tid >> 6;                                             \
    const int lane = tid & 63;                                             \
    const int quad = lane >> 4;                                            \
    const int l16  = lane & 15;                                            \
    const int rowBase = blockIdx.y * 128;                                  \
    const int colBase = blockIdx.x * 128;                                  \
    const int wr = (wid >> 1) * 64;                                        \
    const int wc = (wid & 1) * 64;                                         \
    const int srow = wid * 32 + (lane >> 2);                               \
    const int scol = (lane & 3) * 8;                                       \
    const u16* gA = (A)  + (size_t)(rowBase + srow) * (Kdim) + scol;       \
    const u16* gB = (BT) + (size_t)(colBase + srow) * (Kdim) + scol;       \
    u16* lA0 = &As[(wid * 32) * BK];                                       \
    u16* lA1 = &As[(wid * 32 + 16) * BK];                                  \
    u16* lB0 = &Bs[(wid * 32) * BK];                                       \
    u16* lB1 = &Bs[(wid * 32 + 16) * BK];                                  \
    const size_t row16 = (size_t)16 * (Kdim);                              \
    f32x4 acc[4][4] = {};                                                  \
    for (int k0 = 0; k0 < (Kdim); k0 += BK) {                              \
        GLOAD_LDS16(gA + k0,         lA0);                                 \
        GLOAD_LDS16(gA + k0 + row16, lA1);                                 \
        GLOAD_LDS16(gB + k0,         lB0);                                 \
        GLOAD_LDS16(gB + k0 + row16, lB1);                                 \
        __syncthreads();                                                   \
        short8 a[4], b[4];                                                 \
        _Pragma("unroll")                                                  \
        for (int mi = 0; mi < 4; ++mi)                                     \
            a[mi] = *(const short8*)&As[(wr + mi * 16 + l16) * BK + quad * 8]; \
        _Pragma("unroll")                                                  \
        for (int ni = 0; ni < 4; ++ni)                                     \
            b[ni] = *(const short8*)&Bs[(wc + ni * 16 + l16) * BK + quad * 8]; \
        _Pragma("unroll")                                                  \
        for (int mi = 0; mi < 4; ++mi)                                     \
            _Pragma("unroll")                                              \
            for (int ni = 0; ni < 4; ++ni)                                 \
                acc[mi][ni] = __builtin_amdgcn_mfma_f32_16x16x32_bf16(     \
                    a[mi], b[ni], acc[mi][ni], 0, 0, 0);                   \
        __syncthreads();                                                   \
    }                                                                      \
    const int wRow = rowBase + wr;                                         \
    const int wCol = colBase + wc;

// ------------------------------------------------------- fused QKV GEMM
// C = x @ [Wq | Wk | Wv] (N=3072). Columns: [0,2048) Q -> rope*1/8 -> Qb;
// [2048,2560) K -> rope -> KVb; [2560,3072) V -> plain -> KVb. All branches
// wave-uniform (wCol is 64-aligned, segments 512-aligned).
__global__ __launch_bounds__(256) void gemm_qkv(
    const u16* __restrict__ A, const u16* __restrict__ BT,
    u16* __restrict__ Qb, u16* __restrict__ KVb,
    const float* __restrict__ cosT, const float* __restrict__ sinT) {
    GEMM_BODY(A, BT, DM)

    u16* dst;
    int dstride, dcol;
    float scale;
    bool doRope;
    if (wCol < 2048)      { dst = Qb;  dstride = 2048; dcol = wCol;        scale = 0.125f; doRope = true;  }
    else if (wCol < 2560) { dst = KVb; dstride = 1024; dcol = wCol - 2048; scale = 1.0f;   doRope = true;  }
    else                  { dst = KVb; dstride = 1024; dcol = wCol - 2048; scale = 1.0f;   doRope = false; }

#pragma unroll
    for (int mi = 0; mi < 4; ++mi) {
#pragma unroll
        for (int r = 0; r < 4; ++r) {
            const int R = wRow + mi * 16 + quad * 4 + r;
            u16* crow = dst + (size_t)R * dstride + dcol;
            if (doRope) {
                const int s = R & (SEQ - 1);
#pragma unroll
                for (int ni = 0; ni < 2; ++ni) {
                    const int dl = ni * 16 + l16;           // 0..31
                    float lo = acc[mi][ni][r];
                    float hi = acc[mi][ni + 2][r];
                    float cs = cosT[s * 32 + dl];
                    float sn = sinT[s * 32 + dl];
                    crow[dl]      = f2b((lo * cs - hi * sn) * scale);
                    crow[dl + 32] = f2b((hi * cs + lo * sn) * scale);
                }
            } else {
#pragma unroll
                for (int ni = 0; ni < 4; ++ni)
                    crow[ni * 16 + l16] = f2b(acc[mi][ni][r]);
            }
        }
    }
}

// ------------------------------------------------------- output GEMM (f32)
__global__ __launch_bounds__(256) void gemm_out(
    const u16* __restrict__ A, const u16* __restrict__ BT,
    float* __restrict__ C32) {
    GEMM_BODY(A, BT, DM)
#pragma unroll
    for (int mi = 0; mi < 4; ++mi) {
#pragma unroll
        for (int r = 0; r < 4; ++r) {
            const int R = wRow + mi * 16 + quad * 4 + r;
            float* crow = C32 + (size_t)R * DM + wCol;
#pragma unroll
            for (int ni = 0; ni < 4; ++ni)
                crow[ni * 16 + l16] = acc[mi][ni][r];
        }
    }
}

// ------------------------------------------------------- flash attention
// 512 threads = 8 waves; wave w owns 16 q-rows of a 128-row q-tile.
// Round-8 change: grid (16,32,2) = 1024 blocks, ONE q-tile per block, all
// co-resident at 4 blocks/CU (4 x 39936 B = 156 KB LDS) -> 32 waves/CU,
// double round-7's 16 (grid was the occupancy cap: LDS/VGPR allowed 4
// blocks/CU but only 512 blocks were launched). Causal-triangle imbalance
// is balanced per-CU instead of per-block: with dispatch period 256
// (== 0 mod gridDim.x), blocks landing on one CU flip parity ((h>=16)^b)
// -> qt vs 15-qt, and b rotates bx by 8 -> each CU's 4 resident blocks
// cost {q, 15-q, (q+8)&15, 15-((q+8)&15)} = exactly 68 key-tiles, with a
// mixed large/small concurrency profile. Coverage stays bijective per
// (h,b) regardless of the actual dispatch mapping.
__global__ __launch_bounds__(512, 8) void flash_attn(
    const u16* __restrict__ Q, const u16* __restrict__ KV,
    u16* __restrict__ Y) {
    __shared__ __align__(16) u16 Ks[64 * 64];         // 8 KB, XOR-swizzled
    __shared__ __align__(16) u16 Vt[64 * 72];         // 9 KB, [dim][key]
    __shared__ __align__(16) u16 Ps[8 * 16 * PSTR];   // 22 KB

    const int h   = blockIdx.y;
    const int b   = blockIdx.z;
    const int kvh = h >> 2;
    const int tid  = threadIdx.x;
    const int wid  = tid >> 6;          // 0..7
    const int lane = tid & 63;
    const int quad = lane >> 4;
    const int l16  = lane & 15;

    const u16* Kg = KV + (size_t)b * SEQ * KVSTR + kvh * HD;
    const u16* Vg = Kg + 512;
    u16* Psw = Ps + wid * 16 * PSTR;

    // staging coords (512 threads)
    const int kKey = tid >> 3, kCc = tid & 7;   // K: one 16B chunk/thread
    const int vkp  = tid & 31;                  // V: key pair 2vkp, 2vkp+1
    const int vd0  = (tid >> 5) * 4;            // 4 dims

    // per-CU balanced q-tile assignment (see kernel comment)
    const int bxr = (blockIdx.x + ((b & 1) << 3)) & 15;
    const int par = ((h >> 4) ^ b) & 1;
    const int qt  = par ? (15 - bxr) : bxr;
    const int rowBaseW = qt * 128 + wid * 16;

    // --- preload Q A-frags (Q pre-scaled by 1/8 in GEMM epilogue)
    short8 qf[2];
#pragma unroll
    for (int ks = 0; ks < 2; ++ks)
        qf[ks] = *(const short8*)&Q[
            (size_t)(b * SEQ + rowBaseW + l16) * (NHEADS * HD)
            + h * HD + ks * 32 + quad * 8];

    f32x4 o[4] = {};
    float mi[4], li[4];
#pragma unroll
    for (int r = 0; r < 4; ++r) { mi[r] = -3e38f; li[r] = 0.f; }

    const int nTiles = 2 * qt + 2;

    // --- prefetch tile 0
    short8  kreg = *(const short8*)&Kg[(size_t)kKey * KVSTR + kCc * 8];
    short4v vrA  = *(const short4v*)&Vg[(size_t)(2 * vkp)     * KVSTR + vd0];
    short4v vrB  = *(const short4v*)&Vg[(size_t)(2 * vkp + 1) * KVSTR + vd0];

    for (int t = 0; t < nTiles; ++t) {
        const int j0 = t * 64;
        __syncthreads();   // previous tile's LDS reads done

        // --- write staged K (XOR-swizzled 16B chunks)
        *(short8*)&Ks[kKey * 64 + ((kCc ^ (kKey & 7)) * 8)] = kreg;
        // --- write staged V as packed key-pairs (4 x b32, conflict-free)
#pragma unroll
        for (int i = 0; i < 4; ++i) {
            unsigned int w = (unsigned int)(u16)vrA[i]
                           | ((unsigned int)(u16)vrB[i] << 16);
            ((unsigned int*)Vt)[(vd0 + i) * 36 + vkp] = w;
        }
        __syncthreads();

        // --- prefetch tile t+1 (overlaps with compute below)
        if (t + 1 < nTiles) {
            const size_t jn = (size_t)(j0 + 64);
            kreg = *(const short8*)&Kg[(jn + kKey) * KVSTR + kCc * 8];
            vrA  = *(const short4v*)&Vg[(jn + 2 * vkp)     * KVSTR + vd0];
            vrB  = *(const short4v*)&Vg[(jn + 2 * vkp + 1) * KVSTR + vd0];
        }

        // --- S = Q @ K^T  (8 MFMA)
        f32x4 s[4] = {};
#pragma unroll
        for (int ks = 0; ks < 2; ++ks)
#pragma unroll
            for (int ct = 0; ct < 4; ++ct) {
                int key = ct * 16 + l16;
                int cc  = (ks * 4 + quad) ^ (key & 7);
                short8 bk = *(const short8*)&Ks[key * 64 + cc * 8];
                s[ct] = __builtin_amdgcn_mfma_f32_16x16x32_bf16(
                    qf[ks], bk, s[ct], 0, 0, 0);
            }

        // --- causal mask (gate vs wave MIN row — round-4 lesson)
        if (j0 + 63 > rowBaseW) {
#pragma unroll
            for (int ct = 0; ct < 4; ++ct)
#pragma unroll
                for (int r = 0; r < 4; ++r) {
                    int R = rowBaseW + quad * 4 + r;
                    int J = j0 + ct * 16 + l16;
                    if (J > R) s[ct][r] = -3e38f;
                }
        }

        // --- online softmax (rows = quad*4+r, reduce over l16)
#pragma unroll
        for (int r = 0; r < 4; ++r) {
            float rmax = fmaxf(fmaxf(s[0][r], s[1][r]),
                               fmaxf(s[2][r], s[3][r]));
            rmax = fmaxf(rmax, __shfl_xor(rmax, 1, 64));
            rmax = fmaxf(rmax, __shfl_xor(rmax, 2, 64));
            rmax = fmaxf(rmax, __shfl_xor(rmax, 4, 64));
            rmax = fmaxf(rmax, __shfl_xor(rmax, 8, 64));
            float mnew  = fmaxf(mi[r], rmax);
            float alpha = __expf(mi[r] - mnew);
            mi[r] = mnew;
            float rs = 0.f;
#pragma unroll
            for (int ct = 0; ct < 4; ++ct) {
                float p = __expf(s[ct][r] - mnew);
                s[ct][r] = p;
                rs += p;
                o[ct][r] *= alpha;
            }
            rs += __shfl_xor(rs, 1, 64);
            rs += __shfl_xor(rs, 2, 64);
            rs += __shfl_xor(rs, 4, 64);
            rs += __shfl_xor(rs, 8, 64);
            li[r] = li[r] * alpha + rs;
        }

        // --- P: C-layout -> LDS -> A-layout (wave-private)
#pragma unroll
        for (int ct = 0; ct < 4; ++ct)
#pragma unroll
            for (int r = 0; r < 4; ++r)
                Psw[(quad * 4 + r) * PSTR + ct * 16 + l16] = f2b(s[ct][r]);

        // --- O += P @ V  (8 MFMA)
        short8 pa[2];
#pragma unroll
        for (int ks = 0; ks < 2; ++ks)
            pa[ks] = *(const short8*)&Psw[l16 * PSTR + ks * 32 + quad * 8];
#pragma unroll
        for (int ks = 0; ks < 2; ++ks)
#pragma unroll
            for (int ct = 0; ct < 4; ++ct) {
                short8 vbf = *(const short8*)&Vt[(ct * 16 + l16) * 72 + ks * 32 + quad * 8];
                o[ct] = __builtin_amdgcn_mfma_f32_16x16x32_bf16(
                    pa[ks], vbf, o[ct], 0, 0, 0);
            }
    }

    // --- normalize + store this q-tile
    float rli[4];
#pragma unroll
    for (int r = 0; r < 4; ++r) rli[r] = 1.0f / li[r];
#pragma unroll
    for (int r = 0; r < 4; ++r) {
        int R = rowBaseW + quad * 4 + r;
        u16* yrow = Y + (size_t)(b * SEQ + R) * (NHEADS * HD) + h * HD;
#pragma unroll
        for (int ct = 0; ct < 4; ++ct)
            yrow[ct * 16 + l16] = f2b(o[ct][r] * rli[r]);
    }
}

// ---------------------------------------------------------------- launch
extern "C" void kernel_launch(void* const* d_in, const int* in_sizes, int n_in,
                              void* d_out, int out_size, void* d_ws, size_t ws_size,
                              hipStream_t stream) {
    const float* x  = (const float*)d_in[0];
    const float* Wq = (const float*)d_in[1];
    const float* Wk = (const float*)d_in[2];
    const float* Wv = (const float*)d_in[3];
    const float* Wo = (const float*)d_in[4];
    float* out = (float*)d_out;   // f32 output

    char* ws = (char*)d_ws;
    u16*  xb    = (u16*)(ws);                    // 16 MB  4096x2048 bf16
    u16*  WqkvT = (u16*)(ws + 16777216);         // 12 MB  3072x2048 (Wq|Wk|Wv)^T
    u16*  WoT   = (u16*)(ws + 29360128);         //  8 MB  2048x2048
    u16*  Qb    = (u16*)(ws + 37748736);         // 16 MB  (roped, pre-scaled 1/8)
    u16*  KVb   = (u16*)(ws + 54525952);         //  8 MB  4096x1024 (K roped | V)
    u16*  Yb    = (u16*)(ws + 62914560);         // 16 MB
    float* cosT = (float*)(ws + 79691776);       // 256 KB
    float* sinT = (float*)(ws + 79953920);       // 256 KB

    rope_table_kernel<<<dim3(65536 / 256), 256, 0, stream>>>(cosT, sinT);

    cvt_f32_bf16<<<dim3(MROWS * DM / 4 / 256), 256, 0, stream>>>(x, xb, MROWS * DM / 4);

    dim3 tb(32, 8);
    transpose_f32_bf16<<<dim3(2048/32, 2048/32), tb, 0, stream>>>(Wq, WqkvT, 2048, 2048);
    transpose_f32_bf16<<<dim3( 512/32, 2048/32), tb, 0, stream>>>(Wk, WqkvT + 2048 * 2048, 2048, 512);
    transpose_f32_bf16<<<dim3( 512/32, 2048/32), tb, 0, stream>>>(Wv, WqkvT + 2560 * 2048, 2048, 512);
    transpose_f32_bf16<<<dim3(2048/32, 2048/32), tb, 0, stream>>>(Wo, WoT, 2048, 2048);

    gemm_qkv<<<dim3(24, 32), 256, 0, stream>>>(xb, WqkvT, Qb, KVb, cosT, sinT);

    flash_attn<<<dim3(16, NHEADS, 2), 512, 0, stream>>>(Qb, KVb, Yb);

    gemm_out<<<dim3(16, 32), 256, 0, stream>>>(Yb, WoT, out);
}

// Round 2
// 416.822 us; speedup vs baseline: 1.1751x; 1.1751x over previous
//
#include <hip/hip_runtime.h>
#include <cstdint>

typedef unsigned short u16;
typedef __attribute__((ext_vector_type(8))) short short8;   // bf16x8 MFMA frag
typedef __attribute__((ext_vector_type(4))) short short4v;  // bf16x4
typedef __attribute__((ext_vector_type(4))) float f32x4;    // fp32x4 accumulator

#define SEQ     2048
#define NHEADS  32
#define NKV     8
#define HD      64
#define DM      2048
#define MROWS   4096   // BATCH * SEQ
#define KVSTR   1024   // fused KV row stride (8 K-heads | 8 V-heads)
#define PSTR    88     // Ps row stride (u16): 176B, 16B-aligned, 2-way banks

__device__ __forceinline__ float b2f(unsigned int u) {
    return __builtin_bit_cast(float, u << 16);
}
__device__ __forceinline__ u16 f2b(float f) {
    unsigned int u = __builtin_bit_cast(unsigned int, f);
    return (u16)((u + 0x7fffu + ((u >> 16) & 1u)) >> 16);   // RNE
}

// async global->LDS, 16B per lane; LDS dest = wave-uniform base + lane*16
#define GLOAD_LDS16(g, l)                                              \
    __builtin_amdgcn_global_load_lds(                                  \
        (const __attribute__((address_space(1))) void*)(g),            \
        (__attribute__((address_space(3))) void*)(l), 16, 0, 0)

// ------------------------------------------------------------- f32 -> bf16
__global__ __launch_bounds__(256) void cvt_f32_bf16(
    const float* __restrict__ in, u16* __restrict__ out, int n4) {
    int i = blockIdx.x * 256 + threadIdx.x;
    if (i < n4) {
        float4 v = ((const float4*)in)[i];
        ushort4 o;
        o.x = f2b(v.x); o.y = f2b(v.y); o.z = f2b(v.z); o.w = f2b(v.w);
        ((ushort4*)out)[i] = o;
    }
}

// ------------------------------------------------------------- RoPE tables
__global__ __launch_bounds__(256) void rope_table_kernel(
    float* __restrict__ cosT, float* __restrict__ sinT) {
    int idx = blockIdx.x * 256 + threadIdx.x;     // 65536 = 2048*32
    int s  = idx >> 5;
    int dl = idx & 31;
    float inv_freq = exp2f((float)dl * -0.41524101186092025f); // 10000^(-dl/32)
    float ang = (float)s * inv_freq;
    float sn, cs;
    sincosf(ang, &sn, &cs);                        // accurate (range-reduced)
    cosT[idx] = cs;
    sinT[idx] = sn;
}

// ------------------------------------------------- transpose + downcast
__global__ __launch_bounds__(256) void transpose_f32_bf16(
    const float* __restrict__ in, u16* __restrict__ out, int K, int N) {
    __shared__ float tile[32][33];
    int n0 = blockIdx.x * 32, k0 = blockIdx.y * 32;
    int tx = threadIdx.x, ty = threadIdx.y;   // 32 x 8
    for (int r = ty; r < 32; r += 8)
        tile[r][tx] = in[(size_t)(k0 + r) * N + n0 + tx];
    __syncthreads();
    for (int r = ty; r < 32; r += 8)
        out[(size_t)(n0 + r) * K + k0 + tx] = f2b(tile[tx][r]);
}

// ------------------------------------------------------- GEMM core macro
// 128x128 block tile, 4 waves 2x2 (64x64 each, acc 4x4), BK=32, unpadded
// LDS, global_load_lds width=16 (m97 structure).
#define GEMM_BODY(A, BT, Kdim)                                             \
    constexpr int BK = 32;                                                 \
    __shared__ __align__(16) u16 As[128 * BK];                             \
    __shared__ __align__(16) u16 Bs[128 * BK];                             \
    const int tid  = threadIdx.x;                                          \
    const int wid  = tid >> 6;                                             \
    const int lane = tid & 63;                                             \
    const int quad = lane >> 4;                                            \
    const int l16  = lane & 15;                                            \
    const int rowBase = blockIdx.y * 128;                                  \
    const int colBase = blockIdx.x * 128;                                  \
    const int wr = (wid >> 1) * 64;                                        \
    const int wc = (wid & 1) * 64;                                         \
    const int srow = wid * 32 + (lane >> 2);                               \
    const int scol = (lane & 3) * 8;                                       \
    const u16* gA = (A)  + (size_t)(rowBase + srow) * (Kdim) + scol;       \
    const u16* gB = (BT) + (size_t)(colBase + srow) * (Kdim) + scol;       \
    u16* lA0 = &As[(wid * 32) * BK];                                       \
    u16* lA1 = &As[(wid * 32 + 16) * BK];                                  \
    u16* lB0 = &Bs[(wid * 32) * BK];                                       \
    u16* lB1 = &Bs[(wid * 32 + 16) * BK];                                  \
    const size_t row16 = (size_t)16 * (Kdim);                              \
    f32x4 acc[4][4] = {};                                                  \
    for (int k0 = 0; k0 < (Kdim); k0 += BK) {                              \
        GLOAD_LDS16(gA + k0,         lA0);                                 \
        GLOAD_LDS16(gA + k0 + row16, lA1);                                 \
        GLOAD_LDS16(gB + k0,         lB0);                                 \
        GLOAD_LDS16(gB + k0 + row16, lB1);                                 \
        __syncthreads();                                                   \
        short8 a[4], b[4];                                                 \
        _Pragma("unroll")                                                  \
        for (int mi = 0; mi < 4; ++mi)                                     \
            a[mi] = *(const short8*)&As[(wr + mi * 16 + l16) * BK + quad * 8]; \
        _Pragma("unroll")                                                  \
        for (int ni = 0; ni < 4; ++ni)                                     \
            b[ni] = *(const short8*)&Bs[(wc + ni * 16 + l16) * BK + quad * 8]; \
        _Pragma("unroll")                                                  \
        for (int mi = 0; mi < 4; ++mi)                                     \
            _Pragma("unroll")                                              \
            for (int ni = 0; ni < 4; ++ni)                                 \
                acc[mi][ni] = __builtin_amdgcn_mfma_f32_16x16x32_bf16(     \
                    a[mi], b[ni], acc[mi][ni], 0, 0, 0);                   \
        __syncthreads();                                                   \
    }                                                                      \
    const int wRow = rowBase + wr;                                         \
    const int wCol = colBase + wc;

// ------------------------------------------------------- fused QKV GEMM
// C = x @ [Wq | Wk | Wv] (N=3072). Columns: [0,2048) Q -> rope*1/8 -> Qb;
// [2048,2560) K -> rope -> KVb; [2560,3072) V -> plain -> KVb. All branches
// wave-uniform (wCol is 64-aligned, segments 512-aligned).
__global__ __launch_bounds__(256) void gemm_qkv(
    const u16* __restrict__ A, const u16* __restrict__ BT,
    u16* __restrict__ Qb, u16* __restrict__ KVb,
    const float* __restrict__ cosT, const float* __restrict__ sinT) {
    GEMM_BODY(A, BT, DM)

    u16* dst;
    int dstride, dcol;
    float scale;
    bool doRope;
    if (wCol < 2048)      { dst = Qb;  dstride = 2048; dcol = wCol;        scale = 0.125f; doRope = true;  }
    else if (wCol < 2560) { dst = KVb; dstride = 1024; dcol = wCol - 2048; scale = 1.0f;   doRope = true;  }
    else                  { dst = KVb; dstride = 1024; dcol = wCol - 2048; scale = 1.0f;   doRope = false; }

#pragma unroll
    for (int mi = 0; mi < 4; ++mi) {
#pragma unroll
        for (int r = 0; r < 4; ++r) {
            const int R = wRow + mi * 16 + quad * 4 + r;
            u16* crow = dst + (size_t)R * dstride + dcol;
            if (doRope) {
                const int s = R & (SEQ - 1);
#pragma unroll
                for (int ni = 0; ni < 2; ++ni) {
                    const int dl = ni * 16 + l16;           // 0..31
                    float lo = acc[mi][ni][r];
                    float hi = acc[mi][ni + 2][r];
                    float cs = cosT[s * 32 + dl];
                    float sn = sinT[s * 32 + dl];
                    crow[dl]      = f2b((lo * cs - hi * sn) * scale);
                    crow[dl + 32] = f2b((hi * cs + lo * sn) * scale);
                }
            } else {
#pragma unroll
                for (int ni = 0; ni < 4; ++ni)
                    crow[ni * 16 + l16] = f2b(acc[mi][ni][r]);
            }
        }
    }
}

// ------------------------------------------------------- output GEMM (f32)
__global__ __launch_bounds__(256) void gemm_out(
    const u16* __restrict__ A, const u16* __restrict__ BT,
    float* __restrict__ C32) {
    GEMM_BODY(A, BT, DM)
#pragma unroll
    for (int mi = 0; mi < 4; ++mi) {
#pragma unroll
        for (int r = 0; r < 4; ++r) {
            const int R = wRow + mi * 16 + quad * 4 + r;
            float* crow = C32 + (size_t)R * DM + wCol;
#pragma unroll
            for (int ni = 0; ni < 4; ++ni)
                crow[ni * 16 + l16] = acc[mi][ni][r];
        }
    }
}

// ------------------------------------------------------- flash attention
// 512 threads = 8 waves; wave w owns 16 q-rows of a 128-row q-tile.
// Grid (16,32,2) = 1024 blocks, ONE q-tile per block, 4 blocks/CU
// (4 x 39936 B = 156 KB LDS) -> up to 32 waves/CU.
// ROUND-2 FIX: launch_bounds min-waves/EU back to 4. Round 1's (512,8)
// forced the allocator to 32 VGPRs -> scratch spills (WRITE_SIZE 16->355 MB,
// FETCH 39->290 MB, VALUBusy 44->24%). The (512,4) bound allows up to 128
// VGPRs; the kernel naturally allocates ~60 (<64), so the HW can still
// schedule 8 waves/SIMD = 4 blocks/CU — LDS is the binding limit, not VGPR.
// Causal-triangle imbalance balanced per-CU: with dispatch period 256
// (== 0 mod gridDim.x), blocks landing on one CU flip parity ((h>=16)^b)
// -> qt vs 15-qt, and b rotates bx by 8 -> each CU's 4 resident blocks
// cost {q, 15-q, (q+8)&15, 15-((q+8)&15)} = exactly 68 key-tiles.
// Coverage stays bijective per (h,b) regardless of dispatch mapping.
__global__ __launch_bounds__(512, 4) void flash_attn(
    const u16* __restrict__ Q, const u16* __restrict__ KV,
    u16* __restrict__ Y) {
    __shared__ __align__(16) u16 Ks[64 * 64];         // 8 KB, XOR-swizzled
    __shared__ __align__(16) u16 Vt[64 * 72];         // 9 KB, [dim][key]
    __shared__ __align__(16) u16 Ps[8 * 16 * PSTR];   // 22 KB

    const int h   = blockIdx.y;
    const int b   = blockIdx.z;
    const int kvh = h >> 2;
    const int tid  = threadIdx.x;
    const int wid  = tid >> 6;          // 0..7
    const int lane = tid & 63;
    const int quad = lane >> 4;
    const int l16  = lane & 15;

    const u16* Kg = KV + (size_t)b * SEQ * KVSTR + kvh * HD;
    const u16* Vg = Kg + 512;
    u16* Psw = Ps + wid * 16 * PSTR;

    // staging coords (512 threads)
    const int kKey = tid >> 3, kCc = tid & 7;   // K: one 16B chunk/thread
    const int vkp  = tid & 31;                  // V: key pair 2vkp, 2vkp+1
    const int vd0  = (tid >> 5) * 4;            // 4 dims

    // per-CU balanced q-tile assignment (see kernel comment)
    const int bxr = (blockIdx.x + ((b & 1) << 3)) & 15;
    const int par = ((h >> 4) ^ b) & 1;
    const int qt  = par ? (15 - bxr) : bxr;
    const int rowBaseW = qt * 128 + wid * 16;

    // --- preload Q A-frags (Q pre-scaled by 1/8 in GEMM epilogue)
    short8 qf[2];
#pragma unroll
    for (int ks = 0; ks < 2; ++ks)
        qf[ks] = *(const short8*)&Q[
            (size_t)(b * SEQ + rowBaseW + l16) * (NHEADS * HD)
            + h * HD + ks * 32 + quad * 8];

    f32x4 o[4] = {};
    float mi[4], li[4];
#pragma unroll
    for (int r = 0; r < 4; ++r) { mi[r] = -3e38f; li[r] = 0.f; }

    const int nTiles = 2 * qt + 2;

    // --- prefetch tile 0
    short8  kreg = *(const short8*)&Kg[(size_t)kKey * KVSTR + kCc * 8];
    short4v vrA  = *(const short4v*)&Vg[(size_t)(2 * vkp)     * KVSTR + vd0];
    short4v vrB  = *(const short4v*)&Vg[(size_t)(2 * vkp + 1) * KVSTR + vd0];

    for (int t = 0; t < nTiles; ++t) {
        const int j0 = t * 64;
        __syncthreads();   // previous tile's LDS reads done

        // --- write staged K (XOR-swizzled 16B chunks)
        *(short8*)&Ks[kKey * 64 + ((kCc ^ (kKey & 7)) * 8)] = kreg;
        // --- write staged V as packed key-pairs (4 x b32, conflict-free)
#pragma unroll
        for (int i = 0; i < 4; ++i) {
            unsigned int w = (unsigned int)(u16)vrA[i]
                           | ((unsigned int)(u16)vrB[i] << 16);
            ((unsigned int*)Vt)[(vd0 + i) * 36 + vkp] = w;
        }
        __syncthreads();

        // --- prefetch tile t+1 (overlaps with compute below)
        if (t + 1 < nTiles) {
            const size_t jn = (size_t)(j0 + 64);
            kreg = *(const short8*)&Kg[(jn + kKey) * KVSTR + kCc * 8];
            vrA  = *(const short4v*)&Vg[(jn + 2 * vkp)     * KVSTR + vd0];
            vrB  = *(const short4v*)&Vg[(jn + 2 * vkp + 1) * KVSTR + vd0];
        }

        // --- S = Q @ K^T  (8 MFMA)
        f32x4 s[4] = {};
#pragma unroll
        for (int ks = 0; ks < 2; ++ks)
#pragma unroll
            for (int ct = 0; ct < 4; ++ct) {
                int key = ct * 16 + l16;
                int cc  = (ks * 4 + quad) ^ (key & 7);
                short8 bk = *(const short8*)&Ks[key * 64 + cc * 8];
                s[ct] = __builtin_amdgcn_mfma_f32_16x16x32_bf16(
                    qf[ks], bk, s[ct], 0, 0, 0);
            }

        // --- causal mask (gate vs wave MIN row — round-4 lesson)
        if (j0 + 63 > rowBaseW) {
#pragma unroll
            for (int ct = 0; ct < 4; ++ct)
#pragma unroll
                for (int r = 0; r < 4; ++r) {
                    int R = rowBaseW + quad * 4 + r;
                    int J = j0 + ct * 16 + l16;
                    if (J > R) s[ct][r] = -3e38f;
                }
        }

        // --- online softmax (rows = quad*4+r, reduce over l16)
#pragma unroll
        for (int r = 0; r < 4; ++r) {
            float rmax = fmaxf(fmaxf(s[0][r], s[1][r]),
                               fmaxf(s[2][r], s[3][r]));
            rmax = fmaxf(rmax, __shfl_xor(rmax, 1, 64));
            rmax = fmaxf(rmax, __shfl_xor(rmax, 2, 64));
            rmax = fmaxf(rmax, __shfl_xor(rmax, 4, 64));
            rmax = fmaxf(rmax, __shfl_xor(rmax, 8, 64));
            float mnew  = fmaxf(mi[r], rmax);
            float alpha = __expf(mi[r] - mnew);
            mi[r] = mnew;
            float rs = 0.f;
#pragma unroll
            for (int ct = 0; ct < 4; ++ct) {
                float p = __expf(s[ct][r] - mnew);
                s[ct][r] = p;
                rs += p;
                o[ct][r] *= alpha;
            }
            rs += __shfl_xor(rs, 1, 64);
            rs += __shfl_xor(rs, 2, 64);
            rs += __shfl_xor(rs, 4, 64);
            rs += __shfl_xor(rs, 8, 64);
            li[r] = li[r] * alpha + rs;
        }

        // --- P: C-layout -> LDS -> A-layout (wave-private)
#pragma unroll
        for (int ct = 0; ct < 4; ++ct)
#pragma unroll
            for (int r = 0; r < 4; ++r)
                Psw[(quad * 4 + r) * PSTR + ct * 16 + l16] = f2b(s[ct][r]);

        // --- O += P @ V  (8 MFMA)
        short8 pa[2];
#pragma unroll
        for (int ks = 0; ks < 2; ++ks)
            pa[ks] = *(const short8*)&Psw[l16 * PSTR + ks * 32 + quad * 8];
#pragma unroll
        for (int ks = 0; ks < 2; ++ks)
#pragma unroll
            for (int ct = 0; ct < 4; ++ct) {
                short8 vbf = *(const short8*)&Vt[(ct * 16 + l16) * 72 + ks * 32 + quad * 8];
                o[ct] = __builtin_amdgcn_mfma_f32_16x16x32_bf16(
                    pa[ks], vbf, o[ct], 0, 0, 0);
            }
    }

    // --- normalize + store this q-tile
    float rli[4];
#pragma unroll
    for (int r = 0; r < 4; ++r) rli[r] = 1.0f / li[r];
#pragma unroll
    for (int r = 0; r < 4; ++r) {
        int R = rowBaseW + quad * 4 + r;
        u16* yrow = Y + (size_t)(b * SEQ + R) * (NHEADS * HD) + h * HD;
#pragma unroll
        for (int ct = 0; ct < 4; ++ct)
            yrow[ct * 16 + l16] = f2b(o[ct][r] * rli[r]);
    }
}

// ---------------------------------------------------------------- launch
extern "C" void kernel_launch(void* const* d_in, const int* in_sizes, int n_in,
                              void* d_out, int out_size, void* d_ws, size_t ws_size,
                              hipStream_t stream) {
    const float* x  = (const float*)d_in[0];
    const float* Wq = (const float*)d_in[1];
    const float* Wk = (const float*)d_in[2];
    const float* Wv = (const float*)d_in[3];
    const float* Wo = (const float*)d_in[4];
    float* out = (float*)d_out;   // f32 output

    char* ws = (char*)d_ws;
    u16*  xb    = (u16*)(ws);                    // 16 MB  4096x2048 bf16
    u16*  WqkvT = (u16*)(ws + 16777216);         // 12 MB  3072x2048 (Wq|Wk|Wv)^T
    u16*  WoT   = (u16*)(ws + 29360128);         //  8 MB  2048x2048
    u16*  Qb    = (u16*)(ws + 37748736);         // 16 MB  (roped, pre-scaled 1/8)
    u16*  KVb   = (u16*)(ws + 54525952);         //  8 MB  4096x1024 (K roped | V)
    u16*  Yb    = (u16*)(ws + 62914560);         // 16 MB
    float* cosT = (float*)(ws + 79691776);       // 256 KB
    float* sinT = (float*)(ws + 79953920);       // 256 KB

    rope_table_kernel<<<dim3(65536 / 256), 256, 0, stream>>>(cosT, sinT);

    cvt_f32_bf16<<<dim3(MROWS * DM / 4 / 256), 256, 0, stream>>>(x, xb, MROWS * DM / 4);

    dim3 tb(32, 8);
    transpose_f32_bf16<<<dim3(2048/32, 2048/32), tb, 0, stream>>>(Wq, WqkvT, 2048, 2048);
    transpose_f32_bf16<<<dim3( 512/32, 2048/32), tb, 0, stream>>>(Wk, WqkvT + 2048 * 2048, 2048, 512);
    transpose_f32_bf16<<<dim3( 512/32, 2048/32), tb, 0, stream>>>(Wv, WqkvT + 2560 * 2048, 2048, 512);
    transpose_f32_bf16<<<dim3(2048/32, 2048/32), tb, 0, stream>>>(Wo, WoT, 2048, 2048);

    gemm_qkv<<<dim3(24, 32), 256, 0, stream>>>(xb, WqkvT, Qb, KVb, cosT, sinT);

    flash_attn<<<dim3(16, NHEADS, 2), 512, 0, stream>>>(Qb, KVb, Yb);

    gemm_out<<<dim3(16, 32), 256, 0, stream>>>(Yb, WoT, out);
}

// Round 3
// 403.071 us; speedup vs baseline: 1.2152x; 1.0341x over previous
//
#include <hip/hip_runtime.h>
#include <cstdint>

typedef unsigned short u16;
typedef __attribute__((ext_vector_type(8))) short short8;   // bf16x8 MFMA frag
typedef __attribute__((ext_vector_type(4))) short short4v;  // bf16x4
typedef __attribute__((ext_vector_type(4))) float f32x4;    // fp32x4 accumulator

#define SEQ     2048
#define NHEADS  32
#define NKV     8
#define HD      64
#define DM      2048
#define MROWS   4096   // BATCH * SEQ
#define KVSTR   1024   // fused KV row stride (8 K-heads | 8 V-heads)
#define PSTR    88     // Ps row stride (u16): 176B, 16B-aligned, 2-way banks

__device__ __forceinline__ float b2f(unsigned int u) {
    return __builtin_bit_cast(float, u << 16);
}
__device__ __forceinline__ u16 f2b(float f) {
    unsigned int u = __builtin_bit_cast(unsigned int, f);
    return (u16)((u + 0x7fffu + ((u >> 16) & 1u)) >> 16);   // RNE
}

// async global->LDS, 16B per lane; LDS dest = wave-uniform base + lane*16
#define GLOAD_LDS16(g, l)                                              \
    __builtin_amdgcn_global_load_lds(                                  \
        (const __attribute__((address_space(1))) void*)(g),            \
        (__attribute__((address_space(3))) void*)(l), 16, 0, 0)

// ------------------------------------------------------------- f32 -> bf16
__global__ __launch_bounds__(256) void cvt_f32_bf16(
    const float* __restrict__ in, u16* __restrict__ out, int n4) {
    int i = blockIdx.x * 256 + threadIdx.x;
    if (i < n4) {
        float4 v = ((const float4*)in)[i];
        ushort4 o;
        o.x = f2b(v.x); o.y = f2b(v.y); o.z = f2b(v.z); o.w = f2b(v.w);
        ((ushort4*)out)[i] = o;
    }
}

// ------------------------------------------------------------- RoPE tables
__global__ __launch_bounds__(256) void rope_table_kernel(
    float* __restrict__ cosT, float* __restrict__ sinT) {
    int idx = blockIdx.x * 256 + threadIdx.x;     // 65536 = 2048*32
    int s  = idx >> 5;
    int dl = idx & 31;
    float inv_freq = exp2f((float)dl * -0.41524101186092025f); // 10000^(-dl/32)
    float ang = (float)s * inv_freq;
    float sn, cs;
    sincosf(ang, &sn, &cs);                        // accurate (range-reduced)
    cosT[idx] = cs;
    sinT[idx] = sn;
}

// ------------------------------------------------- transpose + downcast
__global__ __launch_bounds__(256) void transpose_f32_bf16(
    const float* __restrict__ in, u16* __restrict__ out, int K, int N) {
    __shared__ float tile[32][33];
    int n0 = blockIdx.x * 32, k0 = blockIdx.y * 32;
    int tx = threadIdx.x, ty = threadIdx.y;   // 32 x 8
    for (int r = ty; r < 32; r += 8)
        tile[r][tx] = in[(size_t)(k0 + r) * N + n0 + tx];
    __syncthreads();
    for (int r = ty; r < 32; r += 8)
        out[(size_t)(n0 + r) * K + k0 + tx] = f2b(tile[tx][r]);
}

// ------------------------------------------------------- GEMM core macro
// 128x128 block tile, 4 waves 2x2 (64x64 each, acc 4x4), BK=32, unpadded
// LDS, global_load_lds width=16 (m97 structure).
#define GEMM_BODY(A, BT, Kdim)                                             \
    constexpr int BK = 32;                                                 \
    __shared__ __align__(16) u16 As[128 * BK];                             \
    __shared__ __align__(16) u16 Bs[128 * BK];                             \
    const int tid  = threadIdx.x;                                          \
    const int wid  = tid >> 6;                                             \
    const int lane = tid & 63;                                             \
    const int quad = lane >> 4;                                            \
    const int l16  = lane & 15;                                            \
    const int rowBase = blockIdx.y * 128;                                  \
    const int colBase = blockIdx.x * 128;                                  \
    const int wr = (wid >> 1) * 64;                                        \
    const int wc = (wid & 1) * 64;                                         \
    const int srow = wid * 32 + (lane >> 2);                               \
    const int scol = (lane & 3) * 8;                                       \
    const u16* gA = (A)  + (size_t)(rowBase + srow) * (Kdim) + scol;       \
    const u16* gB = (BT) + (size_t)(colBase + srow) * (Kdim) + scol;       \
    u16* lA0 = &As[(wid * 32) * BK];                                       \
    u16* lA1 = &As[(wid * 32 + 16) * BK];                                  \
    u16* lB0 = &Bs[(wid * 32) * BK];                                       \
    u16* lB1 = &Bs[(wid * 32 + 16) * BK];                                  \
    const size_t row16 = (size_t)16 * (Kdim);                              \
    f32x4 acc[4][4] = {};                                                  \
    for (int k0 = 0; k0 < (Kdim); k0 += BK) {                              \
        GLOAD_LDS16(gA + k0,         lA0);                                 \
        GLOAD_LDS16(gA + k0 + row16, lA1);                                 \
        GLOAD_LDS16(gB + k0,         lB0);                                 \
        GLOAD_LDS16(gB + k0 + row16, lB1);                                 \
        __syncthreads();                                                   \
        short8 a[4], b[4];                                                 \
        _Pragma("unroll")                                                  \
        for (int mi = 0; mi < 4; ++mi)                                     \
            a[mi] = *(const short8*)&As[(wr + mi * 16 + l16) * BK + quad * 8]; \
        _Pragma("unroll")                                                  \
        for (int ni = 0; ni < 4; ++ni)                                     \
            b[ni] = *(const short8*)&Bs[(wc + ni * 16 + l16) * BK + quad * 8]; \
        _Pragma("unroll")                                                  \
        for (int mi = 0; mi < 4; ++mi)                                     \
            _Pragma("unroll")                                              \
            for (int ni = 0; ni < 4; ++ni)                                 \
                acc[mi][ni] = __builtin_amdgcn_mfma_f32_16x16x32_bf16(     \
                    a[mi], b[ni], acc[mi][ni], 0, 0, 0);                   \
        __syncthreads();                                                   \
    }                                                                      \
    const int wRow = rowBase + wr;                                         \
    const int wCol = colBase + wc;

// ------------------------------------------------------- fused QKV GEMM
__global__ __launch_bounds__(256) void gemm_qkv(
    const u16* __restrict__ A, const u16* __restrict__ BT,
    u16* __restrict__ Qb, u16* __restrict__ KVb,
    const float* __restrict__ cosT, const float* __restrict__ sinT) {
    GEMM_BODY(A, BT, DM)

    u16* dst;
    int dstride, dcol;
    float scale;
    bool doRope;
    if (wCol < 2048)      { dst = Qb;  dstride = 2048; dcol = wCol;        scale = 0.125f; doRope = true;  }
    else if (wCol < 2560) { dst = KVb; dstride = 1024; dcol = wCol - 2048; scale = 1.0f;   doRope = true;  }
    else                  { dst = KVb; dstride = 1024; dcol = wCol - 2048; scale = 1.0f;   doRope = false; }

#pragma unroll
    for (int mi = 0; mi < 4; ++mi) {
#pragma unroll
        for (int r = 0; r < 4; ++r) {
            const int R = wRow + mi * 16 + quad * 4 + r;
            u16* crow = dst + (size_t)R * dstride + dcol;
            if (doRope) {
                const int s = R & (SEQ - 1);
#pragma unroll
                for (int ni = 0; ni < 2; ++ni) {
                    const int dl = ni * 16 + l16;           // 0..31
                    float lo = acc[mi][ni][r];
                    float hi = acc[mi][ni + 2][r];
                    float cs = cosT[s * 32 + dl];
                    float sn = sinT[s * 32 + dl];
                    crow[dl]      = f2b((lo * cs - hi * sn) * scale);
                    crow[dl + 32] = f2b((hi * cs + lo * sn) * scale);
                }
            } else {
#pragma unroll
                for (int ni = 0; ni < 4; ++ni)
                    crow[ni * 16 + l16] = f2b(acc[mi][ni][r]);
            }
        }
    }
}

// ------------------------------------------------------- output GEMM (f32)
__global__ __launch_bounds__(256) void gemm_out(
    const u16* __restrict__ A, const u16* __restrict__ BT,
    float* __restrict__ C32) {
    GEMM_BODY(A, BT, DM)
#pragma unroll
    for (int mi = 0; mi < 4; ++mi) {
#pragma unroll
        for (int r = 0; r < 4; ++r) {
            const int R = wRow + mi * 16 + quad * 4 + r;
            float* crow = C32 + (size_t)R * DM + wCol;
#pragma unroll
            for (int ni = 0; ni < 4; ++ni)
                crow[ni * 16 + l16] = acc[mi][ni][r];
        }
    }
}

// ------------------------------------------------------- flash attention
// ROUND-3: uniform split-K. Grid (16,32,2) = 1024 blocks; bx = pair*2 + s
// with pair p in [0,8), s in {0,1}. Each block runs TWO phases:
//   phase 0: q-tile p      (cost 2p+2),  key-half s -> (p+1)  tiles
//   phase 1: q-tile 15-p   (cost 32-2p), key-half s -> (16-p) tiles
// Every block = exactly 17 key-tiles -> UNIFORM cost, no dispatch-mapping
// assumptions. 4 blocks/CU by LDS (4 x 39936 = 156 KB) -> 32 waves/CU all
// co-resident (round-2's 1024-block grid had the right capacity but
// imbalanced blocks -> 27% avg occupancy tail; this removes the tail).
// Each phase emits a NORMALIZED partial (o/l) + per-row (m,l):
//   s=0 -> PoA (f32, aliased over dead xb/WqkvT/WoT), s=1 -> Yb (bf16).
// combine_kernel merges with weights lX*exp(mX-m) (fully-masked partials
// get weight exp(-3e38-m)=0, so their garbage o,l never contribute).
// No cross-block sync: if VGPR ever exceeded 64 (-> 2 blocks/CU), blocks
// just queue; uniform cost keeps that efficient (graceful degradation).
__global__ __launch_bounds__(512, 4) void flash_attn(
    const u16* __restrict__ Q, const u16* __restrict__ KV,
    u16* __restrict__ Yb, float* __restrict__ PoA,
    float* __restrict__ Ml) {
    __shared__ __align__(16) u16 Ks[64 * 64];         // 8 KB, XOR-swizzled
    __shared__ __align__(16) u16 Vt[64 * 72];         // 9 KB, [dim][key]
    __shared__ __align__(16) u16 Ps[8 * 16 * PSTR];   // 22 KB

    const int p   = blockIdx.x >> 1;    // pair 0..7
    const int sh  = blockIdx.x & 1;     // key-half 0/1
    const int h   = blockIdx.y;
    const int b   = blockIdx.z;
    const int kvh = h >> 2;
    const int tid  = threadIdx.x;
    const int wid  = tid >> 6;          // 0..7
    const int lane = tid & 63;
    const int quad = lane >> 4;
    const int l16  = lane & 15;

    const u16* Kg = KV + (size_t)b * SEQ * KVSTR + kvh * HD;
    const u16* Vg = Kg + 512;
    u16* Psw = Ps + wid * 16 * PSTR;

    // staging coords (512 threads)
    const int kKey = tid >> 3, kCc = tid & 7;   // K: one 16B chunk/thread
    const int vkp  = tid & 31;                  // V: key pair 2vkp, 2vkp+1
    const int vd0  = (tid >> 5) * 4;            // 4 dims

    for (int ph = 0; ph < 2; ++ph) {
        const int qt = ph ? (15 - p) : p;
        const int hc = ph ? (16 - p) : (p + 1);   // tiles in each key-half
        const int tS = sh * hc;                    // first key-tile index
        const int rowBaseW = qt * 128 + wid * 16;

        // --- preload Q A-frags (Q pre-scaled by 1/8 in GEMM epilogue)
        short8 qf[2];
#pragma unroll
        for (int ks = 0; ks < 2; ++ks)
            qf[ks] = *(const short8*)&Q[
                (size_t)(b * SEQ + rowBaseW + l16) * (NHEADS * HD)
                + h * HD + ks * 32 + quad * 8];

        f32x4 o[4] = {};
        float mi[4], li[4];
#pragma unroll
        for (int r = 0; r < 4; ++r) { mi[r] = -3e38f; li[r] = 0.f; }

        // --- prefetch first tile of this phase's range
        const size_t jF = (size_t)tS * 64;
        short8  kreg = *(const short8*)&Kg[(jF + kKey) * KVSTR + kCc * 8];
        short4v vrA  = *(const short4v*)&Vg[(jF + 2 * vkp)     * KVSTR + vd0];
        short4v vrB  = *(const short4v*)&Vg[(jF + 2 * vkp + 1) * KVSTR + vd0];

        for (int tt = 0; tt < hc; ++tt) {
            const int j0 = (tS + tt) * 64;
            __syncthreads();   // previous tile's LDS reads done

            // --- write staged K (XOR-swizzled 16B chunks)
            *(short8*)&Ks[kKey * 64 + ((kCc ^ (kKey & 7)) * 8)] = kreg;
            // --- write staged V as packed key-pairs (4 x b32, conflict-free)
#pragma unroll
            for (int i = 0; i < 4; ++i) {
                unsigned int w = (unsigned int)(u16)vrA[i]
                               | ((unsigned int)(u16)vrB[i] << 16);
                ((unsigned int*)Vt)[(vd0 + i) * 36 + vkp] = w;
            }
            __syncthreads();

            // --- prefetch tile tt+1 (overlaps with compute below)
            if (tt + 1 < hc) {
                const size_t jn = (size_t)(j0 + 64);
                kreg = *(const short8*)&Kg[(jn + kKey) * KVSTR + kCc * 8];
                vrA  = *(const short4v*)&Vg[(jn + 2 * vkp)     * KVSTR + vd0];
                vrB  = *(const short4v*)&Vg[(jn + 2 * vkp + 1) * KVSTR + vd0];
            }

            // --- S = Q @ K^T  (8 MFMA)
            f32x4 s[4] = {};
#pragma unroll
            for (int ks = 0; ks < 2; ++ks)
#pragma unroll
                for (int ct = 0; ct < 4; ++ct) {
                    int key = ct * 16 + l16;
                    int cc  = (ks * 4 + quad) ^ (key & 7);
                    short8 bk = *(const short8*)&Ks[key * 64 + cc * 8];
                    s[ct] = __builtin_amdgcn_mfma_f32_16x16x32_bf16(
                        qf[ks], bk, s[ct], 0, 0, 0);
                }

            // --- causal mask (gate vs wave MIN row)
            if (j0 + 63 > rowBaseW) {
#pragma unroll
                for (int ct = 0; ct < 4; ++ct)
#pragma unroll
                    for (int r = 0; r < 4; ++r) {
                        int R = rowBaseW + quad * 4 + r;
                        int J = j0 + ct * 16 + l16;
                        if (J > R) s[ct][r] = -3e38f;
                    }
            }

            // --- online softmax (rows = quad*4+r, reduce over l16)
#pragma unroll
            for (int r = 0; r < 4; ++r) {
                float rmax = fmaxf(fmaxf(s[0][r], s[1][r]),
                                   fmaxf(s[2][r], s[3][r]));
                rmax = fmaxf(rmax, __shfl_xor(rmax, 1, 64));
                rmax = fmaxf(rmax, __shfl_xor(rmax, 2, 64));
                rmax = fmaxf(rmax, __shfl_xor(rmax, 4, 64));
                rmax = fmaxf(rmax, __shfl_xor(rmax, 8, 64));
                float mnew  = fmaxf(mi[r], rmax);
                float alpha = __expf(mi[r] - mnew);
                mi[r] = mnew;
                float rs = 0.f;
#pragma unroll
                for (int ct = 0; ct < 4; ++ct) {
                    float pv = __expf(s[ct][r] - mnew);
                    s[ct][r] = pv;
                    rs += pv;
                    o[ct][r] *= alpha;
                }
                rs += __shfl_xor(rs, 1, 64);
                rs += __shfl_xor(rs, 2, 64);
                rs += __shfl_xor(rs, 4, 64);
                rs += __shfl_xor(rs, 8, 64);
                li[r] = li[r] * alpha + rs;
            }

            // --- P: C-layout -> LDS -> A-layout (wave-private)
#pragma unroll
            for (int ct = 0; ct < 4; ++ct)
#pragma unroll
                for (int r = 0; r < 4; ++r)
                    Psw[(quad * 4 + r) * PSTR + ct * 16 + l16] = f2b(s[ct][r]);

            // --- O += P @ V  (8 MFMA)
            short8 pa[2];
#pragma unroll
            for (int ks = 0; ks < 2; ++ks)
                pa[ks] = *(const short8*)&Psw[l16 * PSTR + ks * 32 + quad * 8];
#pragma unroll
            for (int ks = 0; ks < 2; ++ks)
#pragma unroll
                for (int ct = 0; ct < 4; ++ct) {
                    short8 vbf = *(const short8*)&Vt[(ct * 16 + l16) * 72 + ks * 32 + quad * 8];
                    o[ct] = __builtin_amdgcn_mfma_f32_16x16x32_bf16(
                        pa[ks], vbf, o[ct], 0, 0, 0);
                }
        }

        // --- write this phase's normalized partial + (m,l)
        float rli[4];
#pragma unroll
        for (int r = 0; r < 4; ++r)
            rli[r] = li[r] > 0.f ? 1.0f / li[r] : 0.f;   // guard empty rows
        if (sh == 0) {
#pragma unroll
            for (int r = 0; r < 4; ++r) {
                int R = rowBaseW + quad * 4 + r;
                float* arow = PoA + (size_t)(b * SEQ + R) * (NHEADS * HD) + h * HD;
#pragma unroll
                for (int ct = 0; ct < 4; ++ct)
                    arow[ct * 16 + l16] = o[ct][r] * rli[r];
            }
        } else {
#pragma unroll
            for (int r = 0; r < 4; ++r) {
                int R = rowBaseW + quad * 4 + r;
                u16* yrow = Yb + (size_t)(b * SEQ + R) * (NHEADS * HD) + h * HD;
#pragma unroll
                for (int ct = 0; ct < 4; ++ct)
                    yrow[ct * 16 + l16] = f2b(o[ct][r] * rli[r]);
            }
        }
        if (l16 == 0) {
            float2* MlX = (float2*)Ml + (size_t)sh * 131072
                        + ((b * 32 + h) * 2048 + rowBaseW + quad * 4);
#pragma unroll
            for (int r = 0; r < 4; ++r)
                MlX[r] = make_float2(mi[r], li[r]);
        }
    }
}

// ------------------------------------------------------- split-K combine
// y = (lA*e^{mA-m} * oA + lB*e^{mB-m} * oB) / (lA*e^{mA-m} + lB*e^{mB-m})
// oA f32 (PoA), oB bf16 (in Yb); writes final bf16 back into Yb in place.
__global__ __launch_bounds__(256) void combine_kernel(
    const float* __restrict__ PoA, const float* __restrict__ Ml,
    u16* __restrict__ Yb) {
    const size_t e = ((size_t)blockIdx.x * 256 + threadIdx.x) * 8;
    const int rowg = (int)(e >> 11);          // b*2048 + row
    const int c    = (int)(e & 2047);
    const int h    = c >> 6;
    const int bz   = rowg >> 11;
    const int row  = rowg & 2047;
    const int slot = ((bz * 32 + h) * 2048 + row) * 2;
    const float mA = Ml[slot],          lA = Ml[slot + 1];
    const float mB = Ml[262144 + slot], lB = Ml[262144 + slot + 1];
    const float m  = fmaxf(mA, mB);
    const float wA = lA * __expf(mA - m);
    const float wB = lB * __expf(mB - m);
    const float inv = 1.0f / (wA + wB);       // lA > 0 always
    const float a = wA * inv, bw = wB * inv;
    float4 A0 = *(const float4*)(PoA + e);
    float4 A1 = *(const float4*)(PoA + e + 4);
    short8 Bv = *(const short8*)(Yb + e);
    float av[8] = {A0.x, A0.y, A0.z, A0.w, A1.x, A1.y, A1.z, A1.w};
    u16 yo[8];
#pragma unroll
    for (int j = 0; j < 8; ++j)
        yo[j] = f2b(a * av[j] + bw * b2f((unsigned int)(u16)Bv[j]));
    *(short8*)(Yb + e) = *(short8*)yo;
}

// ---------------------------------------------------------------- launch
extern "C" void kernel_launch(void* const* d_in, const int* in_sizes, int n_in,
                              void* d_out, int out_size, void* d_ws, size_t ws_size,
                              hipStream_t stream) {
    const float* x  = (const float*)d_in[0];
    const float* Wq = (const float*)d_in[1];
    const float* Wk = (const float*)d_in[2];
    const float* Wv = (const float*)d_in[3];
    const float* Wo = (const float*)d_in[4];
    float* out = (float*)d_out;   // f32 output

    char* ws = (char*)d_ws;
    u16*  xb    = (u16*)(ws);                    // 16 MB  4096x2048 bf16
    u16*  WqkvT = (u16*)(ws + 16777216);         // 12 MB  3072x2048 (Wq|Wk|Wv)^T
    u16*  WoT   = (u16*)(ws + 29360128);         //  8 MB  2048x2048 [28,36) MB
    u16*  Qb    = (u16*)(ws + 37748736);         // 16 MB  (roped, pre-scaled 1/8)
    u16*  KVb   = (u16*)(ws + 54525952);         //  8 MB  4096x1024 (K roped | V)
    u16*  Yb    = (u16*)(ws + 62914560);         // 16 MB  partial-B then final Y
    float* cosT = (float*)(ws + 79691776);       // 256 KB
    float* sinT = (float*)(ws + 79953920);       // 256 KB
    // flash-phase aliases (xb/WqkvT/WoT dead during attention):
    float* PoA  = (float*)(ws);                  // 32 MB f32 partial-A [0,32)
    float* Ml   = (float*)(ws + 33554432);       //  2 MB (m,l) x {A,B} [32,34)

    rope_table_kernel<<<dim3(65536 / 256), 256, 0, stream>>>(cosT, sinT);

    cvt_f32_bf16<<<dim3(MROWS * DM / 4 / 256), 256, 0, stream>>>(x, xb, MROWS * DM / 4);

    dim3 tb(32, 8);
    transpose_f32_bf16<<<dim3(2048/32, 2048/32), tb, 0, stream>>>(Wq, WqkvT, 2048, 2048);
    transpose_f32_bf16<<<dim3( 512/32, 2048/32), tb, 0, stream>>>(Wk, WqkvT + 2048 * 2048, 2048, 512);
    transpose_f32_bf16<<<dim3( 512/32, 2048/32), tb, 0, stream>>>(Wv, WqkvT + 2560 * 2048, 2048, 512);

    gemm_qkv<<<dim3(24, 32), 256, 0, stream>>>(xb, WqkvT, Qb, KVb, cosT, sinT);

    flash_attn<<<dim3(16, NHEADS, 2), 512, 0, stream>>>(Qb, KVb, Yb, PoA, Ml);

    combine_kernel<<<dim3(4096), 256, 0, stream>>>(PoA, Ml, Yb);

    // Wo transpose AFTER combine: WoT region [28,36) was reused for
    // PoA-tail + Ml during the attention phase (stream is serial).
    transpose_f32_bf16<<<dim3(2048/32, 2048/32), tb, 0, stream>>>(Wo, WoT, 2048, 2048);

    gemm_out<<<dim3(16, 32), 256, 0, stream>>>(Yb, WoT, out);
}

// Round 4
// 376.389 us; speedup vs baseline: 1.3013x; 1.0709x over previous
//
#include <hip/hip_runtime.h>
#include <cstdint>

typedef unsigned short u16;
typedef __attribute__((ext_vector_type(8))) short short8;   // bf16x8 MFMA frag
typedef __attribute__((ext_vector_type(4))) short short4v;  // bf16x4
typedef __attribute__((ext_vector_type(4))) float f32x4;    // fp32x4 accumulator

#define SEQ     2048
#define NHEADS  32
#define NKV     8
#define HD      64
#define DM      2048
#define MROWS   4096   // BATCH * SEQ
#define KVSTR   1024   // fused KV row stride (8 K-heads | 8 V-heads)
#define PSTR    88     // Ps row stride (u16): 176B, 16B-aligned, 2-way banks

__device__ __forceinline__ float b2f(unsigned int u) {
    return __builtin_bit_cast(float, u << 16);
}
__device__ __forceinline__ u16 f2b(float f) {
    unsigned int u = __builtin_bit_cast(unsigned int, f);
    return (u16)((u + 0x7fffu + ((u >> 16) & 1u)) >> 16);   // RNE
}

// ---- DPP 16-lane reductions (VALU pipe — replaces ds_bpermute shuffles).
// Scope: lanes 0-15 of each 16-lane DPP row == our l16 key-reduce scope.
// xor1 (quad_perm [1,0,3,2] = 0xB1), xor2 (quad_perm [2,3,0,1] = 0x4E),
// then row_half_mirror (0x141) merges quads 0-3/4-7, row_mirror (0x140)
// merges halves -> full 16-lane reduction, zero LDS-pipe traffic.
__device__ __forceinline__ float dpp_red_max16(float x) {
    int v = __builtin_bit_cast(int, x);
    x = fmaxf(x, __builtin_bit_cast(float,
        __builtin_amdgcn_update_dpp(v, v, 0xB1, 0xF, 0xF, true)));
    v = __builtin_bit_cast(int, x);
    x = fmaxf(x, __builtin_bit_cast(float,
        __builtin_amdgcn_update_dpp(v, v, 0x4E, 0xF, 0xF, true)));
    v = __builtin_bit_cast(int, x);
    x = fmaxf(x, __builtin_bit_cast(float,
        __builtin_amdgcn_update_dpp(v, v, 0x141, 0xF, 0xF, true)));
    v = __builtin_bit_cast(int, x);
    x = fmaxf(x, __builtin_bit_cast(float,
        __builtin_amdgcn_update_dpp(v, v, 0x140, 0xF, 0xF, true)));
    return x;
}
__device__ __forceinline__ float dpp_red_sum16(float x) {
    int v = __builtin_bit_cast(int, x);
    x = x + __builtin_bit_cast(float,
        __builtin_amdgcn_update_dpp(v, v, 0xB1, 0xF, 0xF, true));
    v = __builtin_bit_cast(int, x);
    x = x + __builtin_bit_cast(float,
        __builtin_amdgcn_update_dpp(v, v, 0x4E, 0xF, 0xF, true));
    v = __builtin_bit_cast(int, x);
    x = x + __builtin_bit_cast(float,
        __builtin_amdgcn_update_dpp(v, v, 0x141, 0xF, 0xF, true));
    v = __builtin_bit_cast(int, x);
    x = x + __builtin_bit_cast(float,
        __builtin_amdgcn_update_dpp(v, v, 0x140, 0xF, 0xF, true));
    return x;
}

// async global->LDS, 16B per lane; LDS dest = wave-uniform base + lane*16
#define GLOAD_LDS16(g, l)                                              \
    __builtin_amdgcn_global_load_lds(                                  \
        (const __attribute__((address_space(1))) void*)(g),            \
        (__attribute__((address_space(3))) void*)(l), 16, 0, 0)

// ------------------------------------------------------------- f32 -> bf16
__global__ __launch_bounds__(256) void cvt_f32_bf16(
    const float* __restrict__ in, u16* __restrict__ out, int n4) {
    int i = blockIdx.x * 256 + threadIdx.x;
    if (i < n4) {
        float4 v = ((const float4*)in)[i];
        ushort4 o;
        o.x = f2b(v.x); o.y = f2b(v.y); o.z = f2b(v.z); o.w = f2b(v.w);
        ((ushort4*)out)[i] = o;
    }
}

// ------------------------------------------------------------- RoPE tables
__global__ __launch_bounds__(256) void rope_table_kernel(
    float* __restrict__ cosT, float* __restrict__ sinT) {
    int idx = blockIdx.x * 256 + threadIdx.x;     // 65536 = 2048*32
    int s  = idx >> 5;
    int dl = idx & 31;
    float inv_freq = exp2f((float)dl * -0.41524101186092025f); // 10000^(-dl/32)
    float ang = (float)s * inv_freq;
    float sn, cs;
    sincosf(ang, &sn, &cs);                        // accurate (range-reduced)
    cosT[idx] = cs;
    sinT[idx] = sn;
}

// ------------------------------------------------- transpose + downcast
__global__ __launch_bounds__(256) void transpose_f32_bf16(
    const float* __restrict__ in, u16* __restrict__ out, int K, int N) {
    __shared__ float tile[32][33];
    int n0 = blockIdx.x * 32, k0 = blockIdx.y * 32;
    int tx = threadIdx.x, ty = threadIdx.y;   // 32 x 8
    for (int r = ty; r < 32; r += 8)
        tile[r][tx] = in[(size_t)(k0 + r) * N + n0 + tx];
    __syncthreads();
    for (int r = ty; r < 32; r += 8)
        out[(size_t)(n0 + r) * K + k0 + tx] = f2b(tile[tx][r]);
}

// ------------------------------------------------------- GEMM core macro
// 128x128 block tile, 4 waves 2x2 (64x64 each, acc 4x4), BK=32, unpadded
// LDS, global_load_lds width=16 (m97 structure).
#define GEMM_BODY(A, BT, Kdim)                                             \
    constexpr int BK = 32;                                                 \
    __shared__ __align__(16) u16 As[128 * BK];                             \
    __shared__ __align__(16) u16 Bs[128 * BK];                             \
    const int tid  = threadIdx.x;                                          \
    const int wid  = tid >> 6;                                             \
    const int lane = tid & 63;                                             \
    const int quad = lane >> 4;                                            \
    const int l16  = lane & 15;                                            \
    const int rowBase = blockIdx.y * 128;                                  \
    const int colBase = blockIdx.x * 128;                                  \
    const int wr = (wid >> 1) * 64;                                        \
    const int wc = (wid & 1) * 64;                                         \
    const int srow = wid * 32 + (lane >> 2);                               \
    const int scol = (lane & 3) * 8;                                       \
    const u16* gA = (A)  + (size_t)(rowBase + srow) * (Kdim) + scol;       \
    const u16* gB = (BT) + (size_t)(colBase + srow) * (Kdim) + scol;       \
    u16* lA0 = &As[(wid * 32) * BK];                                       \
    u16* lA1 = &As[(wid * 32 + 16) * BK];                                  \
    u16* lB0 = &Bs[(wid * 32) * BK];                                       \
    u16* lB1 = &Bs[(wid * 32 + 16) * BK];                                  \
    const size_t row16 = (size_t)16 * (Kdim);                              \
    f32x4 acc[4][4] = {};                                                  \
    for (int k0 = 0; k0 < (Kdim); k0 += BK) {                              \
        GLOAD_LDS16(gA + k0,         lA0);                                 \
        GLOAD_LDS16(gA + k0 + row16, lA1);                                 \
        GLOAD_LDS16(gB + k0,         lB0);                                 \
        GLOAD_LDS16(gB + k0 + row16, lB1);                                 \
        __syncthreads();                                                   \
        short8 a[4], b[4];                                                 \
        _Pragma("unroll")                                                  \
        for (int mi = 0; mi < 4; ++mi)                                     \
            a[mi] = *(const short8*)&As[(wr + mi * 16 + l16) * BK + quad * 8]; \
        _Pragma("unroll")                                                  \
        for (int ni = 0; ni < 4; ++ni)                                     \
            b[ni] = *(const short8*)&Bs[(wc + ni * 16 + l16) * BK + quad * 8]; \
        _Pragma("unroll")                                                  \
        for (int mi = 0; mi < 4; ++mi)                                     \
            _Pragma("unroll")                                              \
            for (int ni = 0; ni < 4; ++ni)                                 \
                acc[mi][ni] = __builtin_amdgcn_mfma_f32_16x16x32_bf16(     \
                    a[mi], b[ni], acc[mi][ni], 0, 0, 0);                   \
        __syncthreads();                                                   \
    }                                                                      \
    const int wRow = rowBase + wr;                                         \
    const int wCol = colBase + wc;

// ------------------------------------------------------- fused QKV GEMM
__global__ __launch_bounds__(256) void gemm_qkv(
    const u16* __restrict__ A, const u16* __restrict__ BT,
    u16* __restrict__ Qb, u16* __restrict__ KVb,
    const float* __restrict__ cosT, const float* __restrict__ sinT) {
    GEMM_BODY(A, BT, DM)

    u16* dst;
    int dstride, dcol;
    float scale;
    bool doRope;
    if (wCol < 2048)      { dst = Qb;  dstride = 2048; dcol = wCol;        scale = 0.125f; doRope = true;  }
    else if (wCol < 2560) { dst = KVb; dstride = 1024; dcol = wCol - 2048; scale = 1.0f;   doRope = true;  }
    else                  { dst = KVb; dstride = 1024; dcol = wCol - 2048; scale = 1.0f;   doRope = false; }

#pragma unroll
    for (int mi = 0; mi < 4; ++mi) {
#pragma unroll
        for (int r = 0; r < 4; ++r) {
            const int R = wRow + mi * 16 + quad * 4 + r;
            u16* crow = dst + (size_t)R * dstride + dcol;
            if (doRope) {
                const int s = R & (SEQ - 1);
#pragma unroll
                for (int ni = 0; ni < 2; ++ni) {
                    const int dl = ni * 16 + l16;           // 0..31
                    float lo = acc[mi][ni][r];
                    float hi = acc[mi][ni + 2][r];
                    float cs = cosT[s * 32 + dl];
                    float sn = sinT[s * 32 + dl];
                    crow[dl]      = f2b((lo * cs - hi * sn) * scale);
                    crow[dl + 32] = f2b((hi * cs + lo * sn) * scale);
                }
            } else {
#pragma unroll
                for (int ni = 0; ni < 4; ++ni)
                    crow[ni * 16 + l16] = f2b(acc[mi][ni][r]);
            }
        }
    }
}

// ------------------------------------------------------- output GEMM (f32)
__global__ __launch_bounds__(256) void gemm_out(
    const u16* __restrict__ A, const u16* __restrict__ BT,
    float* __restrict__ C32) {
    GEMM_BODY(A, BT, DM)
#pragma unroll
    for (int mi = 0; mi < 4; ++mi) {
#pragma unroll
        for (int r = 0; r < 4; ++r) {
            const int R = wRow + mi * 16 + quad * 4 + r;
            float* crow = C32 + (size_t)R * DM + wCol;
#pragma unroll
            for (int ni = 0; ni < 4; ++ni)
                crow[ni * 16 + l16] = acc[mi][ni][r];
        }
    }
}

// ------------------------------------------------------- flash attention
// Uniform split-K (round 3) + ROUND-4: softmax reductions moved from
// __shfl_xor (= ds_bpermute, LDS pipe) to DPP row ops (VALU pipe).
// Rationale: rounds 0/2/3 all land at the same speed with IDENTICAL
// VALUBusy/MfmaUtil/BANK_CONFLICT across different grids -> shared-pipe
// bound. Per-tile LDS-pipe budget was ~540 cy (8 K-b128 + 8 V-b128 +
// 16 P-b16 + 2 P-b128 + stage writes + 32 bpermute ~190cy); 544 wave-
// tiles/CU x 540 = ~294K cy vs 300K cy kernel duration = ~98% LDS busy.
// DPP removes the 190cy bpermute share (-35% LDS-pipe load).
__global__ __launch_bounds__(512, 4) void flash_attn(
    const u16* __restrict__ Q, const u16* __restrict__ KV,
    u16* __restrict__ Yb, float* __restrict__ PoA,
    float* __restrict__ Ml) {
    __shared__ __align__(16) u16 Ks[64 * 64];         // 8 KB, XOR-swizzled
    __shared__ __align__(16) u16 Vt[64 * 72];         // 9 KB, [dim][key]
    __shared__ __align__(16) u16 Ps[8 * 16 * PSTR];   // 22 KB

    const int p   = blockIdx.x >> 1;    // pair 0..7
    const int sh  = blockIdx.x & 1;     // key-half 0/1
    const int h   = blockIdx.y;
    const int b   = blockIdx.z;
    const int kvh = h >> 2;
    const int tid  = threadIdx.x;
    const int wid  = tid >> 6;          // 0..7
    const int lane = tid & 63;
    const int quad = lane >> 4;
    const int l16  = lane & 15;

    const u16* Kg = KV + (size_t)b * SEQ * KVSTR + kvh * HD;
    const u16* Vg = Kg + 512;
    u16* Psw = Ps + wid * 16 * PSTR;

    // staging coords (512 threads)
    const int kKey = tid >> 3, kCc = tid & 7;   // K: one 16B chunk/thread
    const int vkp  = tid & 31;                  // V: key pair 2vkp, 2vkp+1
    const int vd0  = (tid >> 5) * 4;            // 4 dims

    for (int ph = 0; ph < 2; ++ph) {
        const int qt = ph ? (15 - p) : p;
        const int hc = ph ? (16 - p) : (p + 1);   // tiles in each key-half
        const int tS = sh * hc;                    // first key-tile index
        const int rowBaseW = qt * 128 + wid * 16;

        // --- preload Q A-frags (Q pre-scaled by 1/8 in GEMM epilogue)
        short8 qf[2];
#pragma unroll
        for (int ks = 0; ks < 2; ++ks)
            qf[ks] = *(const short8*)&Q[
                (size_t)(b * SEQ + rowBaseW + l16) * (NHEADS * HD)
                + h * HD + ks * 32 + quad * 8];

        f32x4 o[4] = {};
        float mi[4], li[4];
#pragma unroll
        for (int r = 0; r < 4; ++r) { mi[r] = -3e38f; li[r] = 0.f; }

        // --- prefetch first tile of this phase's range
        const size_t jF = (size_t)tS * 64;
        short8  kreg = *(const short8*)&Kg[(jF + kKey) * KVSTR + kCc * 8];
        short4v vrA  = *(const short4v*)&Vg[(jF + 2 * vkp)     * KVSTR + vd0];
        short4v vrB  = *(const short4v*)&Vg[(jF + 2 * vkp + 1) * KVSTR + vd0];

        for (int tt = 0; tt < hc; ++tt) {
            const int j0 = (tS + tt) * 64;
            __syncthreads();   // previous tile's LDS reads done

            // --- write staged K (XOR-swizzled 16B chunks)
            *(short8*)&Ks[kKey * 64 + ((kCc ^ (kKey & 7)) * 8)] = kreg;
            // --- write staged V as packed key-pairs (4 x b32, conflict-free)
#pragma unroll
            for (int i = 0; i < 4; ++i) {
                unsigned int w = (unsigned int)(u16)vrA[i]
                               | ((unsigned int)(u16)vrB[i] << 16);
                ((unsigned int*)Vt)[(vd0 + i) * 36 + vkp] = w;
            }
            __syncthreads();

            // --- prefetch tile tt+1 (overlaps with compute below)
            if (tt + 1 < hc) {
                const size_t jn = (size_t)(j0 + 64);
                kreg = *(const short8*)&Kg[(jn + kKey) * KVSTR + kCc * 8];
                vrA  = *(const short4v*)&Vg[(jn + 2 * vkp)     * KVSTR + vd0];
                vrB  = *(const short4v*)&Vg[(jn + 2 * vkp + 1) * KVSTR + vd0];
            }

            // --- S = Q @ K^T  (8 MFMA)
            f32x4 s[4] = {};
#pragma unroll
            for (int ks = 0; ks < 2; ++ks)
#pragma unroll
                for (int ct = 0; ct < 4; ++ct) {
                    int key = ct * 16 + l16;
                    int cc  = (ks * 4 + quad) ^ (key & 7);
                    short8 bk = *(const short8*)&Ks[key * 64 + cc * 8];
                    s[ct] = __builtin_amdgcn_mfma_f32_16x16x32_bf16(
                        qf[ks], bk, s[ct], 0, 0, 0);
                }

            // --- causal mask (gate vs wave MIN row)
            if (j0 + 63 > rowBaseW) {
#pragma unroll
                for (int ct = 0; ct < 4; ++ct)
#pragma unroll
                    for (int r = 0; r < 4; ++r) {
                        int R = rowBaseW + quad * 4 + r;
                        int J = j0 + ct * 16 + l16;
                        if (J > R) s[ct][r] = -3e38f;
                    }
            }

            // --- online softmax (rows = quad*4+r, reduce over l16 via DPP)
#pragma unroll
            for (int r = 0; r < 4; ++r) {
                float rmax = fmaxf(fmaxf(s[0][r], s[1][r]),
                                   fmaxf(s[2][r], s[3][r]));
                rmax = dpp_red_max16(rmax);
                float mnew  = fmaxf(mi[r], rmax);
                float alpha = __expf(mi[r] - mnew);
                mi[r] = mnew;
                float rs = 0.f;
#pragma unroll
                for (int ct = 0; ct < 4; ++ct) {
                    float pv = __expf(s[ct][r] - mnew);
                    s[ct][r] = pv;
                    rs += pv;
                    o[ct][r] *= alpha;
                }
                rs = dpp_red_sum16(rs);
                li[r] = li[r] * alpha + rs;
            }

            // --- P: C-layout -> LDS -> A-layout (wave-private)
#pragma unroll
            for (int ct = 0; ct < 4; ++ct)
#pragma unroll
                for (int r = 0; r < 4; ++r)
                    Psw[(quad * 4 + r) * PSTR + ct * 16 + l16] = f2b(s[ct][r]);

            // --- O += P @ V  (8 MFMA)
            short8 pa[2];
#pragma unroll
            for (int ks = 0; ks < 2; ++ks)
                pa[ks] = *(const short8*)&Psw[l16 * PSTR + ks * 32 + quad * 8];
#pragma unroll
            for (int ks = 0; ks < 2; ++ks)
#pragma unroll
                for (int ct = 0; ct < 4; ++ct) {
                    short8 vbf = *(const short8*)&Vt[(ct * 16 + l16) * 72 + ks * 32 + quad * 8];
                    o[ct] = __builtin_amdgcn_mfma_f32_16x16x32_bf16(
                        pa[ks], vbf, o[ct], 0, 0, 0);
                }
        }

        // --- write this phase's normalized partial + (m,l)
        float rli[4];
#pragma unroll
        for (int r = 0; r < 4; ++r)
            rli[r] = li[r] > 0.f ? 1.0f / li[r] : 0.f;   // guard empty rows
        if (sh == 0) {
#pragma unroll
            for (int r = 0; r < 4; ++r) {
                int R = rowBaseW + quad * 4 + r;
                float* arow = PoA + (size_t)(b * SEQ + R) * (NHEADS * HD) + h * HD;
#pragma unroll
                for (int ct = 0; ct < 4; ++ct)
                    arow[ct * 16 + l16] = o[ct][r] * rli[r];
            }
        } else {
#pragma unroll
            for (int r = 0; r < 4; ++r) {
                int R = rowBaseW + quad * 4 + r;
                u16* yrow = Yb + (size_t)(b * SEQ + R) * (NHEADS * HD) + h * HD;
#pragma unroll
                for (int ct = 0; ct < 4; ++ct)
                    yrow[ct * 16 + l16] = f2b(o[ct][r] * rli[r]);
            }
        }
        if (l16 == 0) {
            float2* MlX = (float2*)Ml + (size_t)sh * 131072
                        + ((b * 32 + h) * 2048 + rowBaseW + quad * 4);
#pragma unroll
            for (int r = 0; r < 4; ++r)
                MlX[r] = make_float2(mi[r], li[r]);
        }
    }
}

// ------------------------------------------------------- split-K combine
// y = (lA*e^{mA-m} * oA + lB*e^{mB-m} * oB) / (lA*e^{mA-m} + lB*e^{mB-m})
// oA f32 (PoA), oB bf16 (in Yb); writes final bf16 back into Yb in place.
__global__ __launch_bounds__(256) void combine_kernel(
    const float* __restrict__ PoA, const float* __restrict__ Ml,
    u16* __restrict__ Yb) {
    const size_t e = ((size_t)blockIdx.x * 256 + threadIdx.x) * 8;
    const int rowg = (int)(e >> 11);          // b*2048 + row
    const int c    = (int)(e & 2047);
    const int h    = c >> 6;
    const int bz   = rowg >> 11;
    const int row  = rowg & 2047;
    const int slot = ((bz * 32 + h) * 2048 + row) * 2;
    const float mA = Ml[slot],          lA = Ml[slot + 1];
    const float mB = Ml[262144 + slot], lB = Ml[262144 + slot + 1];
    const float m  = fmaxf(mA, mB);
    const float wA = lA * __expf(mA - m);
    const float wB = lB * __expf(mB - m);
    const float inv = 1.0f / (wA + wB);       // lA > 0 always
    const float a = wA * inv, bw = wB * inv;
    float4 A0 = *(const float4*)(PoA + e);
    float4 A1 = *(const float4*)(PoA + e + 4);
    short8 Bv = *(const short8*)(Yb + e);
    float av[8] = {A0.x, A0.y, A0.z, A0.w, A1.x, A1.y, A1.z, A1.w};
    u16 yo[8];
#pragma unroll
    for (int j = 0; j < 8; ++j)
        yo[j] = f2b(a * av[j] + bw * b2f((unsigned int)(u16)Bv[j]));
    *(short8*)(Yb + e) = *(short8*)yo;
}

// ---------------------------------------------------------------- launch
extern "C" void kernel_launch(void* const* d_in, const int* in_sizes, int n_in,
                              void* d_out, int out_size, void* d_ws, size_t ws_size,
                              hipStream_t stream) {
    const float* x  = (const float*)d_in[0];
    const float* Wq = (const float*)d_in[1];
    const float* Wk = (const float*)d_in[2];
    const float* Wv = (const float*)d_in[3];
    const float* Wo = (const float*)d_in[4];
    float* out = (float*)d_out;   // f32 output

    char* ws = (char*)d_ws;
    u16*  xb    = (u16*)(ws);                    // 16 MB  4096x2048 bf16
    u16*  WqkvT = (u16*)(ws + 16777216);         // 12 MB  3072x2048 (Wq|Wk|Wv)^T
    u16*  WoT   = (u16*)(ws + 29360128);         //  8 MB  2048x2048 [28,36) MB
    u16*  Qb    = (u16*)(ws + 37748736);         // 16 MB  (roped, pre-scaled 1/8)
    u16*  KVb   = (u16*)(ws + 54525952);         //  8 MB  4096x1024 (K roped | V)
    u16*  Yb    = (u16*)(ws + 62914560);         // 16 MB  partial-B then final Y
    float* cosT = (float*)(ws + 79691776);       // 256 KB
    float* sinT = (float*)(ws + 79953920);       // 256 KB
    // flash-phase aliases (xb/WqkvT/WoT dead during attention):
    float* PoA  = (float*)(ws);                  // 32 MB f32 partial-A [0,32)
    float* Ml   = (float*)(ws + 33554432);       //  2 MB (m,l) x {A,B} [32,34)

    rope_table_kernel<<<dim3(65536 / 256), 256, 0, stream>>>(cosT, sinT);

    cvt_f32_bf16<<<dim3(MROWS * DM / 4 / 256), 256, 0, stream>>>(x, xb, MROWS * DM / 4);

    dim3 tb(32, 8);
    transpose_f32_bf16<<<dim3(2048/32, 2048/32), tb, 0, stream>>>(Wq, WqkvT, 2048, 2048);
    transpose_f32_bf16<<<dim3( 512/32, 2048/32), tb, 0, stream>>>(Wk, WqkvT + 2048 * 2048, 2048, 512);
    transpose_f32_bf16<<<dim3( 512/32, 2048/32), tb, 0, stream>>>(Wv, WqkvT + 2560 * 2048, 2048, 512);

    gemm_qkv<<<dim3(24, 32), 256, 0, stream>>>(xb, WqkvT, Qb, KVb, cosT, sinT);

    flash_attn<<<dim3(16, NHEADS, 2), 512, 0, stream>>>(Qb, KVb, Yb, PoA, Ml);

    combine_kernel<<<dim3(4096), 256, 0, stream>>>(PoA, Ml, Yb);

    // Wo transpose AFTER combine: WoT region [28,36) was reused for
    // PoA-tail + Ml during the attention phase (stream is serial).
    transpose_f32_bf16<<<dim3(2048/32, 2048/32), tb, 0, stream>>>(Wo, WoT, 2048, 2048);

    gemm_out<<<dim3(16, 32), 256, 0, stream>>>(Yb, WoT, out);
}

// Round 5
// 351.743 us; speedup vs baseline: 1.3925x; 1.0701x over previous
//
#include <hip/hip_runtime.h>
#include <cstdint>

typedef unsigned short u16;
typedef __attribute__((ext_vector_type(8))) short short8;   // bf16x8 MFMA frag
typedef __attribute__((ext_vector_type(4))) short short4v;  // bf16x4
typedef __attribute__((ext_vector_type(4))) float f32x4;    // fp32x4 accumulator

#define SEQ     2048
#define NHEADS  32
#define NKV     8
#define HD      64
#define DM      2048
#define MROWS   4096   // BATCH * SEQ
#define KVSTR   1024   // fused KV row stride (8 K-heads | 8 V-heads)
#define PSTR    88     // Ps row stride (u16): 176B, 16B-aligned, 2-way banks

__device__ __forceinline__ float b2f(unsigned int u) {
    return __builtin_bit_cast(float, u << 16);
}
__device__ __forceinline__ u16 f2b(float f) {
    unsigned int u = __builtin_bit_cast(unsigned int, f);
    return (u16)((u + 0x7fffu + ((u >> 16) & 1u)) >> 16);   // RNE
}

// ---- DPP 16-lane reductions (VALU pipe — round-4 win, keep)
__device__ __forceinline__ float dpp_red_max16(float x) {
    int v = __builtin_bit_cast(int, x);
    x = fmaxf(x, __builtin_bit_cast(float,
        __builtin_amdgcn_update_dpp(v, v, 0xB1, 0xF, 0xF, true)));
    v = __builtin_bit_cast(int, x);
    x = fmaxf(x, __builtin_bit_cast(float,
        __builtin_amdgcn_update_dpp(v, v, 0x4E, 0xF, 0xF, true)));
    v = __builtin_bit_cast(int, x);
    x = fmaxf(x, __builtin_bit_cast(float,
        __builtin_amdgcn_update_dpp(v, v, 0x141, 0xF, 0xF, true)));
    v = __builtin_bit_cast(int, x);
    x = fmaxf(x, __builtin_bit_cast(float,
        __builtin_amdgcn_update_dpp(v, v, 0x140, 0xF, 0xF, true)));
    return x;
}
__device__ __forceinline__ float dpp_red_sum16(float x) {
    int v = __builtin_bit_cast(int, x);
    x = x + __builtin_bit_cast(float,
        __builtin_amdgcn_update_dpp(v, v, 0xB1, 0xF, 0xF, true));
    v = __builtin_bit_cast(int, x);
    x = x + __builtin_bit_cast(float,
        __builtin_amdgcn_update_dpp(v, v, 0x4E, 0xF, 0xF, true));
    v = __builtin_bit_cast(int, x);
    x = x + __builtin_bit_cast(float,
        __builtin_amdgcn_update_dpp(v, v, 0x141, 0xF, 0xF, true));
    v = __builtin_bit_cast(int, x);
    x = x + __builtin_bit_cast(float,
        __builtin_amdgcn_update_dpp(v, v, 0x140, 0xF, 0xF, true));
    return x;
}

// async global->LDS, 16B per lane; LDS dest = WAVE-UNIFORM base + lane*16;
// global source is per-lane (enables source-side swizzle).
#define GLOAD_LDS16(g, l)                                              \
    __builtin_amdgcn_global_load_lds(                                  \
        (const __attribute__((address_space(1))) void*)(g),            \
        (__attribute__((address_space(3))) void*)(l), 16, 0, 0)

// ------------------------------------------------------------- f32 -> bf16
__global__ __launch_bounds__(256) void cvt_f32_bf16(
    const float* __restrict__ in, u16* __restrict__ out, int n4) {
    int i = blockIdx.x * 256 + threadIdx.x;
    if (i < n4) {
        float4 v = ((const float4*)in)[i];
        ushort4 o;
        o.x = f2b(v.x); o.y = f2b(v.y); o.z = f2b(v.z); o.w = f2b(v.w);
        ((ushort4*)out)[i] = o;
    }
}

// ------------------------------------------------------------- RoPE tables
__global__ __launch_bounds__(256) void rope_table_kernel(
    float* __restrict__ cosT, float* __restrict__ sinT) {
    int idx = blockIdx.x * 256 + threadIdx.x;     // 65536 = 2048*32
    int s  = idx >> 5;
    int dl = idx & 31;
    float inv_freq = exp2f((float)dl * -0.41524101186092025f); // 10000^(-dl/32)
    float ang = (float)s * inv_freq;
    float sn, cs;
    sincosf(ang, &sn, &cs);                        // accurate (range-reduced)
    cosT[idx] = cs;
    sinT[idx] = sn;
}

// ------------------------------------------------- transpose + downcast
__global__ __launch_bounds__(256) void transpose_f32_bf16(
    const float* __restrict__ in, u16* __restrict__ out, int K, int N) {
    __shared__ float tile[32][33];
    int n0 = blockIdx.x * 32, k0 = blockIdx.y * 32;
    int tx = threadIdx.x, ty = threadIdx.y;   // 32 x 8
    for (int r = ty; r < 32; r += 8)
        tile[r][tx] = in[(size_t)(k0 + r) * N + n0 + tx];
    __syncthreads();
    for (int r = ty; r < 32; r += 8)
        out[(size_t)(n0 + r) * K + k0 + tx] = f2b(tile[tx][r]);
}

// ------------------------------------------------------- GEMM core macro
// ROUND-5: 128x128 tile, 4 waves 2x2 (64x64 each, acc 4x4), BK=32, with a
// DEPTH-4 staging ring + counted vmcnt (T3/T4) replacing the 2-barrier
// m97 loop (whose per-step vmcnt(0) drain before s_barrier is the known
// ~70% stall, m233). Structure:
//  - ring[4] x (A 8KB + B 8KB) = 64KB LDS -> 2 blocks/CU (8 waves/CU).
//  - stage sub-tile s+3 while computing s; per-thread 4 gload_lds per
//    sub-tile -> steady-state wait vmcnt(8) (2 newer sub-tiles in flight),
//    vmcnt(4)/vmcnt(0) only in the 2-step epilogue. ONE barrier per step.
//  - waitcnt+barrier fused in a single asm volatile("...":::"memory") so
//    no LDS read can hoist above the cross-wave sync (rule 18 analog).
//  - bank-conflict-free ds_read_b128 via slot-swizzle: 16B-slot
//    phys = q*8 + (u ^ (q&7)), q=row>>1, u=(row&1)*4+kgrp. A 16-row
//    column read then covers all 8 bank classes exactly 2x (2-way = free;
//    the old unpadded [row][32] layout was an 8-way conflict). Staging
//    applies the INVERSE permutation on the per-lane GLOBAL source addr,
//    LDS dest stays linear (global_load_lds constraint, rule 21).
//  - s_setprio(1) around the MFMA cluster (T5).
#define GEMM_BODY(Aptr, BTptr, Kdim)                                        \
    __shared__ __align__(16) u16 rA[4][4096];                               \
    __shared__ __align__(16) u16 rB[4][4096];                               \
    const int tid  = threadIdx.x;                                           \
    const int wid  = tid >> 6;                                              \
    const int lane = tid & 63;                                              \
    const int quad = lane >> 4;                                             \
    const int l16  = lane & 15;                                             \
    const int rowBase = blockIdx.y * 128;                                   \
    const int colBase = blockIdx.x * 128;                                   \
    const int wr = (wid >> 1) * 64;                                         \
    const int wc = (wid & 1) * 64;                                          \
    size_t sAoff[2], sBoff[2];                                              \
    int ldOff[2];                                                           \
    _Pragma("unroll")                                                       \
    for (int j = 0; j < 2; ++j) {                                           \
        const int p = j * 256 + tid;      /* phys 16B slot this thread fills */ \
        const int q = p >> 3;                                               \
        const int u = (p & 7) ^ (q & 7);  /* inverse swizzle */             \
        const int r = (q << 1) | (u >> 2);                                  \
        const int sc = (u & 3) * 8;       /* k-subgroup (elements) */       \
        sAoff[j] = (size_t)(rowBase + r) * (Kdim) + sc;                     \
        sBoff[j] = (size_t)(colBase + r) * (Kdim) + sc;                     \
        ldOff[j] = (j * 256 + (wid << 6)) * 8;   /* wave-uniform, u16 units */ \
    }                                                                       \
    int aOff[4], bOff[4];                 /* swizzled read offsets (u16) */ \
    _Pragma("unroll")                                                       \
    for (int mi = 0; mi < 4; ++mi) {                                        \
        const int ra = wr + mi * 16 + l16;                                  \
        const int qa = ra >> 1;                                             \
        const int ua = ((ra & 1) << 2) | quad;                              \
        aOff[mi] = (qa * 8 + (ua ^ (qa & 7))) * 8;                          \
        const int rb = wc + mi * 16 + l16;                                  \
        const int qb = rb >> 1;                                             \
        const int ub = ((rb & 1) << 2) | quad;                              \
        bOff[mi] = (qb * 8 + (ub ^ (qb & 7))) * 8;                          \
    }                                                                       \
    f32x4 acc[4][4] = {};                                                   \
    const int NT = (Kdim) / 32;                                             \
    _Pragma("unroll")                                                       \
    for (int st = 0; st < 3; ++st) {      /* prologue: stage tiles 0,1,2 */ \
        _Pragma("unroll")                                                   \
        for (int j = 0; j < 2; ++j) {                                       \
            GLOAD_LDS16(Aptr  + sAoff[j] + st * 32, &rA[st][ldOff[j]]);     \
            GLOAD_LDS16(BTptr + sBoff[j] + st * 32, &rB[st][ldOff[j]]);     \
        }                                                                   \
    }                                                                       \
    for (int s = 0; s < NT; ++s) {                                          \
        if (s < NT - 2)                                                     \
            asm volatile("s_waitcnt vmcnt(8)\n\ts_barrier" ::: "memory");   \
        else if (s == NT - 2)                                               \
            asm volatile("s_waitcnt vmcnt(4)\n\ts_barrier" ::: "memory");   \
        else                                                                \
            asm volatile("s_waitcnt vmcnt(0)\n\ts_barrier" ::: "memory");   \
        const u16* Ab = rA[s & 3];                                          \
        const u16* Bb = rB[s & 3];                                          \
        short8 a[4], b[4];                                                  \
        _Pragma("unroll")                                                   \
        for (int mi = 0; mi < 4; ++mi) a[mi] = *(const short8*)&Ab[aOff[mi]]; \
        _Pragma("unroll")                                                   \
        for (int ni = 0; ni < 4; ++ni) b[ni] = *(const short8*)&Bb[bOff[ni]]; \
        if (s + 3 < NT) {                 /* stage sub-tile s+3 */          \
            const int bi = (s + 3) & 3;                                     \
            const int kk = (s + 3) * 32;                                    \
            _Pragma("unroll")                                               \
            for (int j = 0; j < 2; ++j) {                                   \
                GLOAD_LDS16(Aptr  + sAoff[j] + kk, &rA[bi][ldOff[j]]);      \
                GLOAD_LDS16(BTptr + sBoff[j] + kk, &rB[bi][ldOff[j]]);      \
            }                                                               \
        }                                                                   \
        __builtin_amdgcn_s_setprio(1);                                      \
        _Pragma("unroll")                                                   \
        for (int mi = 0; mi < 4; ++mi)                                      \
            _Pragma("unroll")                                               \
            for (int ni = 0; ni < 4; ++ni)                                  \
                acc[mi][ni] = __builtin_amdgcn_mfma_f32_16x16x32_bf16(      \
                    a[mi], b[ni], acc[mi][ni], 0, 0, 0);                    \
        __builtin_amdgcn_s_setprio(0);                                      \
    }                                                                       \
    const int wRow = rowBase + wr;                                          \
    const int wCol = colBase + wc;

// ------------------------------------------------------- fused QKV GEMM
__global__ __launch_bounds__(256, 2) void gemm_qkv(
    const u16* __restrict__ A, const u16* __restrict__ BT,
    u16* __restrict__ Qb, u16* __restrict__ KVb,
    const float* __restrict__ cosT, const float* __restrict__ sinT) {
    GEMM_BODY(A, BT, DM)

    u16* dst;
    int dstride, dcol;
    float scale;
    bool doRope;
    if (wCol < 2048)      { dst = Qb;  dstride = 2048; dcol = wCol;        scale = 0.125f; doRope = true;  }
    else if (wCol < 2560) { dst = KVb; dstride = 1024; dcol = wCol - 2048; scale = 1.0f;   doRope = true;  }
    else                  { dst = KVb; dstride = 1024; dcol = wCol - 2048; scale = 1.0f;   doRope = false; }

#pragma unroll
    for (int mi = 0; mi < 4; ++mi) {
#pragma unroll
        for (int r = 0; r < 4; ++r) {
            const int R = wRow + mi * 16 + quad * 4 + r;
            u16* crow = dst + (size_t)R * dstride + dcol;
            if (doRope) {
                const int s = R & (SEQ - 1);
#pragma unroll
                for (int ni = 0; ni < 2; ++ni) {
                    const int dl = ni * 16 + l16;           // 0..31
                    float lo = acc[mi][ni][r];
                    float hi = acc[mi][ni + 2][r];
                    float cs = cosT[s * 32 + dl];
                    float sn = sinT[s * 32 + dl];
                    crow[dl]      = f2b((lo * cs - hi * sn) * scale);
                    crow[dl + 32] = f2b((hi * cs + lo * sn) * scale);
                }
            } else {
#pragma unroll
                for (int ni = 0; ni < 4; ++ni)
                    crow[ni * 16 + l16] = f2b(acc[mi][ni][r]);
            }
        }
    }
}

// ------------------------------------------------------- output GEMM (f32)
__global__ __launch_bounds__(256, 2) void gemm_out(
    const u16* __restrict__ A, const u16* __restrict__ BT,
    float* __restrict__ C32) {
    GEMM_BODY(A, BT, DM)
#pragma unroll
    for (int mi = 0; mi < 4; ++mi) {
#pragma unroll
        for (int r = 0; r < 4; ++r) {
            const int R = wRow + mi * 16 + quad * 4 + r;
            float* crow = C32 + (size_t)R * DM + wCol;
#pragma unroll
            for (int ni = 0; ni < 4; ++ni)
                crow[ni * 16 + l16] = acc[mi][ni][r];
        }
    }
}

// ------------------------------------------------------- flash attention
// Uniform split-K (round 3) + DPP softmax (round 4). Unchanged this round.
__global__ __launch_bounds__(512, 4) void flash_attn(
    const u16* __restrict__ Q, const u16* __restrict__ KV,
    u16* __restrict__ Yb, float* __restrict__ PoA,
    float* __restrict__ Ml) {
    __shared__ __align__(16) u16 Ks[64 * 64];         // 8 KB, XOR-swizzled
    __shared__ __align__(16) u16 Vt[64 * 72];         // 9 KB, [dim][key]
    __shared__ __align__(16) u16 Ps[8 * 16 * PSTR];   // 22 KB

    const int p   = blockIdx.x >> 1;    // pair 0..7
    const int sh  = blockIdx.x & 1;     // key-half 0/1
    const int h   = blockIdx.y;
    const int b   = blockIdx.z;
    const int kvh = h >> 2;
    const int tid  = threadIdx.x;
    const int wid  = tid >> 6;          // 0..7
    const int lane = tid & 63;
    const int quad = lane >> 4;
    const int l16  = lane & 15;

    const u16* Kg = KV + (size_t)b * SEQ * KVSTR + kvh * HD;
    const u16* Vg = Kg + 512;
    u16* Psw = Ps + wid * 16 * PSTR;

    // staging coords (512 threads)
    const int kKey = tid >> 3, kCc = tid & 7;   // K: one 16B chunk/thread
    const int vkp  = tid & 31;                  // V: key pair 2vkp, 2vkp+1
    const int vd0  = (tid >> 5) * 4;            // 4 dims

    for (int ph = 0; ph < 2; ++ph) {
        const int qt = ph ? (15 - p) : p;
        const int hc = ph ? (16 - p) : (p + 1);   // tiles in each key-half
        const int tS = sh * hc;                    // first key-tile index
        const int rowBaseW = qt * 128 + wid * 16;

        // --- preload Q A-frags (Q pre-scaled by 1/8 in GEMM epilogue)
        short8 qf[2];
#pragma unroll
        for (int ks = 0; ks < 2; ++ks)
            qf[ks] = *(const short8*)&Q[
                (size_t)(b * SEQ + rowBaseW + l16) * (NHEADS * HD)
                + h * HD + ks * 32 + quad * 8];

        f32x4 o[4] = {};
        float mi[4], li[4];
#pragma unroll
        for (int r = 0; r < 4; ++r) { mi[r] = -3e38f; li[r] = 0.f; }

        // --- prefetch first tile of this phase's range
        const size_t jF = (size_t)tS * 64;
        short8  kreg = *(const short8*)&Kg[(jF + kKey) * KVSTR + kCc * 8];
        short4v vrA  = *(const short4v*)&Vg[(jF + 2 * vkp)     * KVSTR + vd0];
        short4v vrB  = *(const short4v*)&Vg[(jF + 2 * vkp + 1) * KVSTR + vd0];

        for (int tt = 0; tt < hc; ++tt) {
            const int j0 = (tS + tt) * 64;
            __syncthreads();   // previous tile's LDS reads done

            // --- write staged K (XOR-swizzled 16B chunks)
            *(short8*)&Ks[kKey * 64 + ((kCc ^ (kKey & 7)) * 8)] = kreg;
            // --- write staged V as packed key-pairs (4 x b32, conflict-free)
#pragma unroll
            for (int i = 0; i < 4; ++i) {
                unsigned int w = (unsigned int)(u16)vrA[i]
                               | ((unsigned int)(u16)vrB[i] << 16);
                ((unsigned int*)Vt)[(vd0 + i) * 36 + vkp] = w;
            }
            __syncthreads();

            // --- prefetch tile tt+1 (overlaps with compute below)
            if (tt + 1 < hc) {
                const size_t jn = (size_t)(j0 + 64);
                kreg = *(const short8*)&Kg[(jn + kKey) * KVSTR + kCc * 8];
                vrA  = *(const short4v*)&Vg[(jn + 2 * vkp)     * KVSTR + vd0];
                vrB  = *(const short4v*)&Vg[(jn + 2 * vkp + 1) * KVSTR + vd0];
            }

            // --- S = Q @ K^T  (8 MFMA)
            f32x4 s[4] = {};
#pragma unroll
            for (int ks = 0; ks < 2; ++ks)
#pragma unroll
                for (int ct = 0; ct < 4; ++ct) {
                    int key = ct * 16 + l16;
                    int cc  = (ks * 4 + quad) ^ (key & 7);
                    short8 bk = *(const short8*)&Ks[key * 64 + cc * 8];
                    s[ct] = __builtin_amdgcn_mfma_f32_16x16x32_bf16(
                        qf[ks], bk, s[ct], 0, 0, 0);
                }

            // --- causal mask (gate vs wave MIN row)
            if (j0 + 63 > rowBaseW) {
#pragma unroll
                for (int ct = 0; ct < 4; ++ct)
#pragma unroll
                    for (int r = 0; r < 4; ++r) {
                        int R = rowBaseW + quad * 4 + r;
                        int J = j0 + ct * 16 + l16;
                        if (J > R) s[ct][r] = -3e38f;
                    }
            }

            // --- online softmax (rows = quad*4+r, reduce over l16 via DPP)
#pragma unroll
            for (int r = 0; r < 4; ++r) {
                float rmax = fmaxf(fmaxf(s[0][r], s[1][r]),
                                   fmaxf(s[2][r], s[3][r]));
                rmax = dpp_red_max16(rmax);
                float mnew  = fmaxf(mi[r], rmax);
                float alpha = __expf(mi[r] - mnew);
                mi[r] = mnew;
                float rs = 0.f;
#pragma unroll
                for (int ct = 0; ct < 4; ++ct) {
                    float pv = __expf(s[ct][r] - mnew);
                    s[ct][r] = pv;
                    rs += pv;
                    o[ct][r] *= alpha;
                }
                rs = dpp_red_sum16(rs);
                li[r] = li[r] * alpha + rs;
            }

            // --- P: C-layout -> LDS -> A-layout (wave-private)
#pragma unroll
            for (int ct = 0; ct < 4; ++ct)
#pragma unroll
                for (int r = 0; r < 4; ++r)
                    Psw[(quad * 4 + r) * PSTR + ct * 16 + l16] = f2b(s[ct][r]);

            // --- O += P @ V  (8 MFMA)
            short8 pa[2];
#pragma unroll
            for (int ks = 0; ks < 2; ++ks)
                pa[ks] = *(const short8*)&Psw[l16 * PSTR + ks * 32 + quad * 8];
#pragma unroll
            for (int ks = 0; ks < 2; ++ks)
#pragma unroll
                for (int ct = 0; ct < 4; ++ct) {
                    short8 vbf = *(const short8*)&Vt[(ct * 16 + l16) * 72 + ks * 32 + quad * 8];
                    o[ct] = __builtin_amdgcn_mfma_f32_16x16x32_bf16(
                        pa[ks], vbf, o[ct], 0, 0, 0);
                }
        }

        // --- write this phase's normalized partial + (m,l)
        float rli[4];
#pragma unroll
        for (int r = 0; r < 4; ++r)
            rli[r] = li[r] > 0.f ? 1.0f / li[r] : 0.f;   // guard empty rows
        if (sh == 0) {
#pragma unroll
            for (int r = 0; r < 4; ++r) {
                int R = rowBaseW + quad * 4 + r;
                float* arow = PoA + (size_t)(b * SEQ + R) * (NHEADS * HD) + h * HD;
#pragma unroll
                for (int ct = 0; ct < 4; ++ct)
                    arow[ct * 16 + l16] = o[ct][r] * rli[r];
            }
        } else {
#pragma unroll
            for (int r = 0; r < 4; ++r) {
                int R = rowBaseW + quad * 4 + r;
                u16* yrow = Yb + (size_t)(b * SEQ + R) * (NHEADS * HD) + h * HD;
#pragma unroll
                for (int ct = 0; ct < 4; ++ct)
                    yrow[ct * 16 + l16] = f2b(o[ct][r] * rli[r]);
            }
        }
        if (l16 == 0) {
            float2* MlX = (float2*)Ml + (size_t)sh * 131072
                        + ((b * 32 + h) * 2048 + rowBaseW + quad * 4);
#pragma unroll
            for (int r = 0; r < 4; ++r)
                MlX[r] = make_float2(mi[r], li[r]);
        }
    }
}

// ------------------------------------------------------- split-K combine
__global__ __launch_bounds__(256) void combine_kernel(
    const float* __restrict__ PoA, const float* __restrict__ Ml,
    u16* __restrict__ Yb) {
    const size_t e = ((size_t)blockIdx.x * 256 + threadIdx.x) * 8;
    const int rowg = (int)(e >> 11);          // b*2048 + row
    const int c    = (int)(e & 2047);
    const int h    = c >> 6;
    const int bz   = rowg >> 11;
    const int row  = rowg & 2047;
    const int slot = ((bz * 32 + h) * 2048 + row) * 2;
    const float mA = Ml[slot],          lA = Ml[slot + 1];
    const float mB = Ml[262144 + slot], lB = Ml[262144 + slot + 1];
    const float m  = fmaxf(mA, mB);
    const float wA = lA * __expf(mA - m);
    const float wB = lB * __expf(mB - m);
    const float inv = 1.0f / (wA + wB);       // lA > 0 always
    const float a = wA * inv, bw = wB * inv;
    float4 A0 = *(const float4*)(PoA + e);
    float4 A1 = *(const float4*)(PoA + e + 4);
    short8 Bv = *(const short8*)(Yb + e);
    float av[8] = {A0.x, A0.y, A0.z, A0.w, A1.x, A1.y, A1.z, A1.w};
    u16 yo[8];
#pragma unroll
    for (int j = 0; j < 8; ++j)
        yo[j] = f2b(a * av[j] + bw * b2f((unsigned int)(u16)Bv[j]));
    *(short8*)(Yb + e) = *(short8*)yo;
}

// ---------------------------------------------------------------- launch
extern "C" void kernel_launch(void* const* d_in, const int* in_sizes, int n_in,
                              void* d_out, int out_size, void* d_ws, size_t ws_size,
                              hipStream_t stream) {
    const float* x  = (const float*)d_in[0];
    const float* Wq = (const float*)d_in[1];
    const float* Wk = (const float*)d_in[2];
    const float* Wv = (const float*)d_in[3];
    const float* Wo = (const float*)d_in[4];
    float* out = (float*)d_out;   // f32 output

    char* ws = (char*)d_ws;
    u16*  xb    = (u16*)(ws);                    // 16 MB  4096x2048 bf16
    u16*  WqkvT = (u16*)(ws + 16777216);         // 12 MB  3072x2048 (Wq|Wk|Wv)^T
    u16*  WoT   = (u16*)(ws + 29360128);         //  8 MB  2048x2048 [28,36) MB
    u16*  Qb    = (u16*)(ws + 37748736);         // 16 MB  (roped, pre-scaled 1/8)
    u16*  KVb   = (u16*)(ws + 54525952);         //  8 MB  4096x1024 (K roped | V)
    u16*  Yb    = (u16*)(ws + 62914560);         // 16 MB  partial-B then final Y
    float* cosT = (float*)(ws + 79691776);       // 256 KB
    float* sinT = (float*)(ws + 79953920);       // 256 KB
    // flash-phase aliases (xb/WqkvT/WoT dead during attention):
    float* PoA  = (float*)(ws);                  // 32 MB f32 partial-A [0,32)
    float* Ml   = (float*)(ws + 33554432);       //  2 MB (m,l) x {A,B} [32,34)

    rope_table_kernel<<<dim3(65536 / 256), 256, 0, stream>>>(cosT, sinT);

    cvt_f32_bf16<<<dim3(MROWS * DM / 4 / 256), 256, 0, stream>>>(x, xb, MROWS * DM / 4);

    dim3 tb(32, 8);
    transpose_f32_bf16<<<dim3(2048/32, 2048/32), tb, 0, stream>>>(Wq, WqkvT, 2048, 2048);
    transpose_f32_bf16<<<dim3( 512/32, 2048/32), tb, 0, stream>>>(Wk, WqkvT + 2048 * 2048, 2048, 512);
    transpose_f32_bf16<<<dim3( 512/32, 2048/32), tb, 0, stream>>>(Wv, WqkvT + 2560 * 2048, 2048, 512);

    gemm_qkv<<<dim3(24, 32), 256, 0, stream>>>(xb, WqkvT, Qb, KVb, cosT, sinT);

    flash_attn<<<dim3(16, NHEADS, 2), 512, 0, stream>>>(Qb, KVb, Yb, PoA, Ml);

    combine_kernel<<<dim3(4096), 256, 0, stream>>>(PoA, Ml, Yb);

    // Wo transpose AFTER combine: WoT region [28,36) was reused for
    // PoA-tail + Ml during the attention phase (stream is serial).
    transpose_f32_bf16<<<dim3(2048/32, 2048/32), tb, 0, stream>>>(Wo, WoT, 2048, 2048);

    gemm_out<<<dim3(16, 32), 256, 0, stream>>>(Yb, WoT, out);
}

// Round 6
// 342.394 us; speedup vs baseline: 1.4305x; 1.0273x over previous
//
#include <hip/hip_runtime.h>
#include <cstdint>

typedef unsigned short u16;
typedef __attribute__((ext_vector_type(8))) short short8;   // bf16x8 MFMA frag
typedef __attribute__((ext_vector_type(4))) short short4v;  // bf16x4
typedef __attribute__((ext_vector_type(4))) float f32x4;    // fp32x4 accumulator

#define SEQ     2048
#define NHEADS  32
#define NKV     8
#define HD      64
#define DM      2048
#define MROWS   4096   // BATCH * SEQ
#define KVSTR   1024   // fused KV row stride (8 K-heads | 8 V-heads)
#define PSTR    88     // Ps row stride (u16): 176B, 16B-aligned, 2-way banks

__device__ __forceinline__ float b2f(unsigned int u) {
    return __builtin_bit_cast(float, u << 16);
}
__device__ __forceinline__ u16 f2b(float f) {
    unsigned int u = __builtin_bit_cast(unsigned int, f);
    return (u16)((u + 0x7fffu + ((u >> 16) & 1u)) >> 16);   // RNE
}

// ---- DPP 16-lane reductions (VALU pipe — round-4 win, keep)
__device__ __forceinline__ float dpp_red_max16(float x) {
    int v = __builtin_bit_cast(int, x);
    x = fmaxf(x, __builtin_bit_cast(float,
        __builtin_amdgcn_update_dpp(v, v, 0xB1, 0xF, 0xF, true)));
    v = __builtin_bit_cast(int, x);
    x = fmaxf(x, __builtin_bit_cast(float,
        __builtin_amdgcn_update_dpp(v, v, 0x4E, 0xF, 0xF, true)));
    v = __builtin_bit_cast(int, x);
    x = fmaxf(x, __builtin_bit_cast(float,
        __builtin_amdgcn_update_dpp(v, v, 0x141, 0xF, 0xF, true)));
    v = __builtin_bit_cast(int, x);
    x = fmaxf(x, __builtin_bit_cast(float,
        __builtin_amdgcn_update_dpp(v, v, 0x140, 0xF, 0xF, true)));
    return x;
}
__device__ __forceinline__ float dpp_red_sum16(float x) {
    int v = __builtin_bit_cast(int, x);
    x = x + __builtin_bit_cast(float,
        __builtin_amdgcn_update_dpp(v, v, 0xB1, 0xF, 0xF, true));
    v = __builtin_bit_cast(int, x);
    x = x + __builtin_bit_cast(float,
        __builtin_amdgcn_update_dpp(v, v, 0x4E, 0xF, 0xF, true));
    v = __builtin_bit_cast(int, x);
    x = x + __builtin_bit_cast(float,
        __builtin_amdgcn_update_dpp(v, v, 0x141, 0xF, 0xF, true));
    v = __builtin_bit_cast(int, x);
    x = x + __builtin_bit_cast(float,
        __builtin_amdgcn_update_dpp(v, v, 0x140, 0xF, 0xF, true));
    return x;
}

// async global->LDS, 16B per lane; LDS dest = WAVE-UNIFORM base + lane*16;
// global source is per-lane (enables source-side swizzle).
#define GLOAD_LDS16(g, l)                                              \
    __builtin_amdgcn_global_load_lds(                                  \
        (const __attribute__((address_space(1))) void*)(g),            \
        (__attribute__((address_space(3))) void*)(l), 16, 0, 0)

// ------------------------------------------------------------- f32 -> bf16
__global__ __launch_bounds__(256) void cvt_f32_bf16(
    const float* __restrict__ in, u16* __restrict__ out, int n4) {
    int i = blockIdx.x * 256 + threadIdx.x;
    if (i < n4) {
        float4 v = ((const float4*)in)[i];
        ushort4 o;
        o.x = f2b(v.x); o.y = f2b(v.y); o.z = f2b(v.z); o.w = f2b(v.w);
        ((ushort4*)out)[i] = o;
    }
}

// ------------------------------------------------------------- RoPE tables
__global__ __launch_bounds__(256) void rope_table_kernel(
    float* __restrict__ cosT, float* __restrict__ sinT) {
    int idx = blockIdx.x * 256 + threadIdx.x;     // 65536 = 2048*32
    int s  = idx >> 5;
    int dl = idx & 31;
    float inv_freq = exp2f((float)dl * -0.41524101186092025f); // 10000^(-dl/32)
    float ang = (float)s * inv_freq;
    float sn, cs;
    sincosf(ang, &sn, &cs);                        // accurate (range-reduced)
    cosT[idx] = cs;
    sinT[idx] = sn;
}

// ------------------------------------------------- transpose + downcast
__global__ __launch_bounds__(256) void transpose_f32_bf16(
    const float* __restrict__ in, u16* __restrict__ out, int K, int N) {
    __shared__ float tile[32][33];
    int n0 = blockIdx.x * 32, k0 = blockIdx.y * 32;
    int tx = threadIdx.x, ty = threadIdx.y;   // 32 x 8
    for (int r = ty; r < 32; r += 8)
        tile[r][tx] = in[(size_t)(k0 + r) * N + n0 + tx];
    __syncthreads();
    for (int r = ty; r < 32; r += 8)
        out[(size_t)(n0 + r) * K + k0 + tx] = f2b(tile[tx][r]);
}

// ------------------------------------------------------- GEMM core macro
// ROUND-6: depth-3 ring (was 4). Round-5 post-mortem: the 64KB depth-4
// ring halved occupancy to 2 blocks/CU (2 waves/SIMD) — traded m97's
// wave-level overlap (m114) for the no-drain schedule, net only +10%.
// Depth-3 = 48KB LDS -> 3 blocks/CU (3 waves/SIMD, VGPR<=170 via
// launch_bounds(256,3)), keeping the counted-vmcnt schedule:
//  - prologue stages tiles 0,1,2; step s waits vmcnt(4) (tiles s+1,s+2
//    in flight = 8 loads, oldest 4 = tile s retired), vmcnt(0) only at
//    the last step. NEVER drains mid-loop.
//  - staging tile s+2 (distance 2 ~ 500cy) covers L2-hit latency (~200cy);
//    reuses buffer of tile s-1 whose reads completed before this step's
//    barrier -> race-free (same argument as round-5, refcheck'd).
//  - bank-conflict-free ds_read_b128 via slot-swizzle (round 5, keep):
//    phys16Bslot = q*8 + (u ^ (q&7)), q=row>>1, u=(row&1)*4+kgrp; staging
//    pre-applies the inverse permutation on the per-lane GLOBAL source
//    (LDS dest stays linear — global_load_lds constraint).
//  - XCD-chunked bijective block swizzle (T1): nwg%8==0 for both GEMMs
//    (768, 512); each XCD gets a contiguous M-panel chunk for L2 locality.
//  - s_setprio(1) around the MFMA cluster (T5).
#define GEMM_BODY(Aptr, BTptr, Kdim)                                        \
    __shared__ __align__(16) u16 rA[3][4096];                               \
    __shared__ __align__(16) u16 rB[3][4096];                               \
    const int tid  = threadIdx.x;                                           \
    const int wid  = tid >> 6;                                              \
    const int lane = tid & 63;                                              \
    const int quad = lane >> 4;                                             \
    const int l16  = lane & 15;                                             \
    const int nwg  = gridDim.x * gridDim.y;                                 \
    const int fid  = blockIdx.y * gridDim.x + blockIdx.x;                   \
    const int swz  = (fid & 7) * (nwg >> 3) + (fid >> 3);                   \
    const int rowBase = (swz / gridDim.x) * 128;                            \
    const int colBase = (swz % gridDim.x) * 128;                            \
    const int wr = (wid >> 1) * 64;                                         \
    const int wc = (wid & 1) * 64;                                          \
    size_t sAoff[2], sBoff[2];                                              \
    int ldOff[2];                                                           \
    _Pragma("unroll")                                                       \
    for (int j = 0; j < 2; ++j) {                                           \
        const int p = j * 256 + tid;      /* phys 16B slot this thread fills */ \
        const int q = p >> 3;                                               \
        const int u = (p & 7) ^ (q & 7);  /* inverse swizzle */             \
        const int r = (q << 1) | (u >> 2);                                  \
        const int sc = (u & 3) * 8;       /* k-subgroup (elements) */       \
        sAoff[j] = (size_t)(rowBase + r) * (Kdim) + sc;                     \
        sBoff[j] = (size_t)(colBase + r) * (Kdim) + sc;                     \
        ldOff[j] = (j * 256 + (wid << 6)) * 8;   /* wave-uniform, u16 units */ \
    }                                                                       \
    int aOff[4], bOff[4];                 /* swizzled read offsets (u16) */ \
    _Pragma("unroll")                                                       \
    for (int mi = 0; mi < 4; ++mi) {                                        \
        const int ra = wr + mi * 16 + l16;                                  \
        const int qa = ra >> 1;                                             \
        const int ua = ((ra & 1) << 2) | quad;                              \
        aOff[mi] = (qa * 8 + (ua ^ (qa & 7))) * 8;                          \
        const int rb = wc + mi * 16 + l16;                                  \
        const int qb = rb >> 1;                                             \
        const int ub = ((rb & 1) << 2) | quad;                              \
        bOff[mi] = (qb * 8 + (ub ^ (qb & 7))) * 8;                          \
    }                                                                       \
    f32x4 acc[4][4] = {};                                                   \
    const int NT = (Kdim) / 32;                                             \
    _Pragma("unroll")                                                       \
    for (int st = 0; st < 3; ++st) {      /* prologue: stage tiles 0,1,2 */ \
        _Pragma("unroll")                                                   \
        for (int j = 0; j < 2; ++j) {                                       \
            GLOAD_LDS16(Aptr  + sAoff[j] + st * 32, &rA[st][ldOff[j]]);     \
            GLOAD_LDS16(BTptr + sBoff[j] + st * 32, &rB[st][ldOff[j]]);     \
        }                                                                   \
    }                                                                       \
    int bs = 0;                           /* s % 3, tracked incrementally */ \
    for (int s = 0; s < NT; ++s) {                                          \
        if (s < NT - 1)                                                     \
            asm volatile("s_waitcnt vmcnt(4)\n\ts_barrier" ::: "memory");   \
        else                                                                \
            asm volatile("s_waitcnt vmcnt(0)\n\ts_barrier" ::: "memory");   \
        const u16* Ab = rA[bs];                                             \
        const u16* Bb = rB[bs];                                             \
        short8 a[4], b[4];                                                  \
        _Pragma("unroll")                                                   \
        for (int mi = 0; mi < 4; ++mi) a[mi] = *(const short8*)&Ab[aOff[mi]]; \
        _Pragma("unroll")                                                   \
        for (int ni = 0; ni < 4; ++ni) b[ni] = *(const short8*)&Bb[bOff[ni]]; \
        if (s + 2 < NT) {                 /* stage sub-tile s+2 */          \
            const int bi = bs == 0 ? 2 : bs - 1;   /* (s+2)%3 */            \
            const int kk = (s + 2) * 32;                                    \
            _Pragma("unroll")                                               \
            for (int j = 0; j < 2; ++j) {                                   \
                GLOAD_LDS16(Aptr  + sAoff[j] + kk, &rA[bi][ldOff[j]]);      \
                GLOAD_LDS16(BTptr + sBoff[j] + kk, &rB[bi][ldOff[j]]);      \
            }                                                               \
        }                                                                   \
        __builtin_amdgcn_s_setprio(1);                                      \
        _Pragma("unroll")                                                   \
        for (int mi = 0; mi < 4; ++mi)                                      \
            _Pragma("unroll")                                               \
            for (int ni = 0; ni < 4; ++ni)                                  \
                acc[mi][ni] = __builtin_amdgcn_mfma_f32_16x16x32_bf16(      \
                    a[mi], b[ni], acc[mi][ni], 0, 0, 0);                    \
        __builtin_amdgcn_s_setprio(0);                                      \
        bs = bs == 2 ? 0 : bs + 1;                                          \
    }                                                                       \
    const int wRow = rowBase + wr;                                          \
    const int wCol = colBase + wc;

// ------------------------------------------------------- fused QKV GEMM
__global__ __launch_bounds__(256, 3) void gemm_qkv(
    const u16* __restrict__ A, const u16* __restrict__ BT,
    u16* __restrict__ Qb, u16* __restrict__ KVb,
    const float* __restrict__ cosT, const float* __restrict__ sinT) {
    GEMM_BODY(A, BT, DM)

    u16* dst;
    int dstride, dcol;
    float scale;
    bool doRope;
    if (wCol < 2048)      { dst = Qb;  dstride = 2048; dcol = wCol;        scale = 0.125f; doRope = true;  }
    else if (wCol < 2560) { dst = KVb; dstride = 1024; dcol = wCol - 2048; scale = 1.0f;   doRope = true;  }
    else                  { dst = KVb; dstride = 1024; dcol = wCol - 2048; scale = 1.0f;   doRope = false; }

#pragma unroll
    for (int mi = 0; mi < 4; ++mi) {
#pragma unroll
        for (int r = 0; r < 4; ++r) {
            const int R = wRow + mi * 16 + quad * 4 + r;
            u16* crow = dst + (size_t)R * dstride + dcol;
            if (doRope) {
                const int s = R & (SEQ - 1);
#pragma unroll
                for (int ni = 0; ni < 2; ++ni) {
                    const int dl = ni * 16 + l16;           // 0..31
                    float lo = acc[mi][ni][r];
                    float hi = acc[mi][ni + 2][r];
                    float cs = cosT[s * 32 + dl];
                    float sn = sinT[s * 32 + dl];
                    crow[dl]      = f2b((lo * cs - hi * sn) * scale);
                    crow[dl + 32] = f2b((hi * cs + lo * sn) * scale);
                }
            } else {
#pragma unroll
                for (int ni = 0; ni < 4; ++ni)
                    crow[ni * 16 + l16] = f2b(acc[mi][ni][r]);
            }
        }
    }
}

// ------------------------------------------------------- output GEMM (f32)
__global__ __launch_bounds__(256, 3) void gemm_out(
    const u16* __restrict__ A, const u16* __restrict__ BT,
    float* __restrict__ C32) {
    GEMM_BODY(A, BT, DM)
#pragma unroll
    for (int mi = 0; mi < 4; ++mi) {
#pragma unroll
        for (int r = 0; r < 4; ++r) {
            const int R = wRow + mi * 16 + quad * 4 + r;
            float* crow = C32 + (size_t)R * DM + wCol;
#pragma unroll
            for (int ni = 0; ni < 4; ++ni)
                crow[ni * 16 + l16] = acc[mi][ni][r];
        }
    }
}

// ------------------------------------------------------- flash attention
// Uniform split-K (round 3) + DPP softmax (round 4). Unchanged this round.
__global__ __launch_bounds__(512, 4) void flash_attn(
    const u16* __restrict__ Q, const u16* __restrict__ KV,
    u16* __restrict__ Yb, float* __restrict__ PoA,
    float* __restrict__ Ml) {
    __shared__ __align__(16) u16 Ks[64 * 64];         // 8 KB, XOR-swizzled
    __shared__ __align__(16) u16 Vt[64 * 72];         // 9 KB, [dim][key]
    __shared__ __align__(16) u16 Ps[8 * 16 * PSTR];   // 22 KB

    const int p   = blockIdx.x >> 1;    // pair 0..7
    const int sh  = blockIdx.x & 1;     // key-half 0/1
    const int h   = blockIdx.y;
    const int b   = blockIdx.z;
    const int kvh = h >> 2;
    const int tid  = threadIdx.x;
    const int wid  = tid >> 6;          // 0..7
    const int lane = tid & 63;
    const int quad = lane >> 4;
    const int l16  = lane & 15;

    const u16* Kg = KV + (size_t)b * SEQ * KVSTR + kvh * HD;
    const u16* Vg = Kg + 512;
    u16* Psw = Ps + wid * 16 * PSTR;

    // staging coords (512 threads)
    const int kKey = tid >> 3, kCc = tid & 7;   // K: one 16B chunk/thread
    const int vkp  = tid & 31;                  // V: key pair 2vkp, 2vkp+1
    const int vd0  = (tid >> 5) * 4;            // 4 dims

    for (int ph = 0; ph < 2; ++ph) {
        const int qt = ph ? (15 - p) : p;
        const int hc = ph ? (16 - p) : (p + 1);   // tiles in each key-half
        const int tS = sh * hc;                    // first key-tile index
        const int rowBaseW = qt * 128 + wid * 16;

        // --- preload Q A-frags (Q pre-scaled by 1/8 in GEMM epilogue)
        short8 qf[2];
#pragma unroll
        for (int ks = 0; ks < 2; ++ks)
            qf[ks] = *(const short8*)&Q[
                (size_t)(b * SEQ + rowBaseW + l16) * (NHEADS * HD)
                + h * HD + ks * 32 + quad * 8];

        f32x4 o[4] = {};
        float mi[4], li[4];
#pragma unroll
        for (int r = 0; r < 4; ++r) { mi[r] = -3e38f; li[r] = 0.f; }

        // --- prefetch first tile of this phase's range
        const size_t jF = (size_t)tS * 64;
        short8  kreg = *(const short8*)&Kg[(jF + kKey) * KVSTR + kCc * 8];
        short4v vrA  = *(const short4v*)&Vg[(jF + 2 * vkp)     * KVSTR + vd0];
        short4v vrB  = *(const short4v*)&Vg[(jF + 2 * vkp + 1) * KVSTR + vd0];

        for (int tt = 0; tt < hc; ++tt) {
            const int j0 = (tS + tt) * 64;
            __syncthreads();   // previous tile's LDS reads done

            // --- write staged K (XOR-swizzled 16B chunks)
            *(short8*)&Ks[kKey * 64 + ((kCc ^ (kKey & 7)) * 8)] = kreg;
            // --- write staged V as packed key-pairs (4 x b32, conflict-free)
#pragma unroll
            for (int i = 0; i < 4; ++i) {
                unsigned int w = (unsigned int)(u16)vrA[i]
                               | ((unsigned int)(u16)vrB[i] << 16);
                ((unsigned int*)Vt)[(vd0 + i) * 36 + vkp] = w;
            }
            __syncthreads();

            // --- prefetch tile tt+1 (overlaps with compute below)
            if (tt + 1 < hc) {
                const size_t jn = (size_t)(j0 + 64);
                kreg = *(const short8*)&Kg[(jn + kKey) * KVSTR + kCc * 8];
                vrA  = *(const short4v*)&Vg[(jn + 2 * vkp)     * KVSTR + vd0];
                vrB  = *(const short4v*)&Vg[(jn + 2 * vkp + 1) * KVSTR + vd0];
            }

            // --- S = Q @ K^T  (8 MFMA)
            f32x4 s[4] = {};
#pragma unroll
            for (int ks = 0; ks < 2; ++ks)
#pragma unroll
                for (int ct = 0; ct < 4; ++ct) {
                    int key = ct * 16 + l16;
                    int cc  = (ks * 4 + quad) ^ (key & 7);
                    short8 bk = *(const short8*)&Ks[key * 64 + cc * 8];
                    s[ct] = __builtin_amdgcn_mfma_f32_16x16x32_bf16(
                        qf[ks], bk, s[ct], 0, 0, 0);
                }

            // --- causal mask (gate vs wave MIN row)
            if (j0 + 63 > rowBaseW) {
#pragma unroll
                for (int ct = 0; ct < 4; ++ct)
#pragma unroll
                    for (int r = 0; r < 4; ++r) {
                        int R = rowBaseW + quad * 4 + r;
                        int J = j0 + ct * 16 + l16;
                        if (J > R) s[ct][r] = -3e38f;
                    }
            }

            // --- online softmax (rows = quad*4+r, reduce over l16 via DPP)
#pragma unroll
            for (int r = 0; r < 4; ++r) {
                float rmax = fmaxf(fmaxf(s[0][r], s[1][r]),
                                   fmaxf(s[2][r], s[3][r]));
                rmax = dpp_red_max16(rmax);
                float mnew  = fmaxf(mi[r], rmax);
                float alpha = __expf(mi[r] - mnew);
                mi[r] = mnew;
                float rs = 0.f;
#pragma unroll
                for (int ct = 0; ct < 4; ++ct) {
                    float pv = __expf(s[ct][r] - mnew);
                    s[ct][r] = pv;
                    rs += pv;
                    o[ct][r] *= alpha;
                }
                rs = dpp_red_sum16(rs);
                li[r] = li[r] * alpha + rs;
            }

            // --- P: C-layout -> LDS -> A-layout (wave-private)
#pragma unroll
            for (int ct = 0; ct < 4; ++ct)
#pragma unroll
                for (int r = 0; r < 4; ++r)
                    Psw[(quad * 4 + r) * PSTR + ct * 16 + l16] = f2b(s[ct][r]);

            // --- O += P @ V  (8 MFMA)
            short8 pa[2];
#pragma unroll
            for (int ks = 0; ks < 2; ++ks)
                pa[ks] = *(const short8*)&Psw[l16 * PSTR + ks * 32 + quad * 8];
#pragma unroll
            for (int ks = 0; ks < 2; ++ks)
#pragma unroll
                for (int ct = 0; ct < 4; ++ct) {
                    short8 vbf = *(const short8*)&Vt[(ct * 16 + l16) * 72 + ks * 32 + quad * 8];
                    o[ct] = __builtin_amdgcn_mfma_f32_16x16x32_bf16(
                        pa[ks], vbf, o[ct], 0, 0, 0);
                }
        }

        // --- write this phase's normalized partial + (m,l)
        float rli[4];
#pragma unroll
        for (int r = 0; r < 4; ++r)
            rli[r] = li[r] > 0.f ? 1.0f / li[r] : 0.f;   // guard empty rows
        if (sh == 0) {
#pragma unroll
            for (int r = 0; r < 4; ++r) {
                int R = rowBaseW + quad * 4 + r;
                float* arow = PoA + (size_t)(b * SEQ + R) * (NHEADS * HD) + h * HD;
#pragma unroll
                for (int ct = 0; ct < 4; ++ct)
                    arow[ct * 16 + l16] = o[ct][r] * rli[r];
            }
        } else {
#pragma unroll
            for (int r = 0; r < 4; ++r) {
                int R = rowBaseW + quad * 4 + r;
                u16* yrow = Yb + (size_t)(b * SEQ + R) * (NHEADS * HD) + h * HD;
#pragma unroll
                for (int ct = 0; ct < 4; ++ct)
                    yrow[ct * 16 + l16] = f2b(o[ct][r] * rli[r]);
            }
        }
        if (l16 == 0) {
            float2* MlX = (float2*)Ml + (size_t)sh * 131072
                        + ((b * 32 + h) * 2048 + rowBaseW + quad * 4);
#pragma unroll
            for (int r = 0; r < 4; ++r)
                MlX[r] = make_float2(mi[r], li[r]);
        }
    }
}

// ------------------------------------------------------- split-K combine
__global__ __launch_bounds__(256) void combine_kernel(
    const float* __restrict__ PoA, const float* __restrict__ Ml,
    u16* __restrict__ Yb) {
    const size_t e = ((size_t)blockIdx.x * 256 + threadIdx.x) * 8;
    const int rowg = (int)(e >> 11);          // b*2048 + row
    const int c    = (int)(e & 2047);
    const int h    = c >> 6;
    const int bz   = rowg >> 11;
    const int row  = rowg & 2047;
    const int slot = ((bz * 32 + h) * 2048 + row) * 2;
    const float mA = Ml[slot],          lA = Ml[slot + 1];
    const float mB = Ml[262144 + slot], lB = Ml[262144 + slot + 1];
    const float m  = fmaxf(mA, mB);
    const float wA = lA * __expf(mA - m);
    const float wB = lB * __expf(mB - m);
    const float inv = 1.0f / (wA + wB);       // lA > 0 always
    const float a = wA * inv, bw = wB * inv;
    float4 A0 = *(const float4*)(PoA + e);
    float4 A1 = *(const float4*)(PoA + e + 4);
    short8 Bv = *(const short8*)(Yb + e);
    float av[8] = {A0.x, A0.y, A0.z, A0.w, A1.x, A1.y, A1.z, A1.w};
    u16 yo[8];
#pragma unroll
    for (int j = 0; j < 8; ++j)
        yo[j] = f2b(a * av[j] + bw * b2f((unsigned int)(u16)Bv[j]));
    *(short8*)(Yb + e) = *(short8*)yo;
}

// ---------------------------------------------------------------- launch
extern "C" void kernel_launch(void* const* d_in, const int* in_sizes, int n_in,
                              void* d_out, int out_size, void* d_ws, size_t ws_size,
                              hipStream_t stream) {
    const float* x  = (const float*)d_in[0];
    const float* Wq = (const float*)d_in[1];
    const float* Wk = (const float*)d_in[2];
    const float* Wv = (const float*)d_in[3];
    const float* Wo = (const float*)d_in[4];
    float* out = (float*)d_out;   // f32 output

    char* ws = (char*)d_ws;
    u16*  xb    = (u16*)(ws);                    // 16 MB  4096x2048 bf16
    u16*  WqkvT = (u16*)(ws + 16777216);         // 12 MB  3072x2048 (Wq|Wk|Wv)^T
    u16*  WoT   = (u16*)(ws + 29360128);         //  8 MB  2048x2048 [28,36) MB
    u16*  Qb    = (u16*)(ws + 37748736);         // 16 MB  (roped, pre-scaled 1/8)
    u16*  KVb   = (u16*)(ws + 54525952);         //  8 MB  4096x1024 (K roped | V)
    u16*  Yb    = (u16*)(ws + 62914560);         // 16 MB  partial-B then final Y
    float* cosT = (float*)(ws + 79691776);       // 256 KB
    float* sinT = (float*)(ws + 79953920);       // 256 KB
    // flash-phase aliases (xb/WqkvT/WoT dead during attention):
    float* PoA  = (float*)(ws);                  // 32 MB f32 partial-A [0,32)
    float* Ml   = (float*)(ws + 33554432);       //  2 MB (m,l) x {A,B} [32,34)

    rope_table_kernel<<<dim3(65536 / 256), 256, 0, stream>>>(cosT, sinT);

    cvt_f32_bf16<<<dim3(MROWS * DM / 4 / 256), 256, 0, stream>>>(x, xb, MROWS * DM / 4);

    dim3 tb(32, 8);
    transpose_f32_bf16<<<dim3(2048/32, 2048/32), tb, 0, stream>>>(Wq, WqkvT, 2048, 2048);
    transpose_f32_bf16<<<dim3( 512/32, 2048/32), tb, 0, stream>>>(Wk, WqkvT + 2048 * 2048, 2048, 512);
    transpose_f32_bf16<<<dim3( 512/32, 2048/32), tb, 0, stream>>>(Wv, WqkvT + 2560 * 2048, 2048, 512);

    gemm_qkv<<<dim3(24, 32), 256, 0, stream>>>(xb, WqkvT, Qb, KVb, cosT, sinT);

    flash_attn<<<dim3(16, NHEADS, 2), 512, 0, stream>>>(Qb, KVb, Yb, PoA, Ml);

    combine_kernel<<<dim3(4096), 256, 0, stream>>>(PoA, Ml, Yb);

    // Wo transpose AFTER combine: WoT region [28,36) was reused for
    // PoA-tail + Ml during the attention phase (stream is serial).
    transpose_f32_bf16<<<dim3(2048/32, 2048/32), tb, 0, stream>>>(Wo, WoT, 2048, 2048);

    gemm_out<<<dim3(16, 32), 256, 0, stream>>>(Yb, WoT, out);
}